// Round 2
// baseline (27370.239 us; speedup 1.0000x reference)
//
#include <hip/hip_runtime.h>
#include <math.h>
#include <cstdint>

#define BB 32
#define LL 256
#define TT 8192     // B*L
#define DIN 256
#define WEDm 200
#define PEDm 56
#define HH 512
#define G4 2048
#define MM 1024
#define EE 100
#define NTAGS 16

// ---------------- K1: embedding concat ----------------
__global__ void k_embed(const int* __restrict__ word, const int* __restrict__ posi,
                        const float* __restrict__ wemb, const float* __restrict__ pemb,
                        float* __restrict__ X) {
  int t = blockIdx.x;
  int c = threadIdx.x * 4;
  float4 v;
  if (c < WEDm) {
    int w = word[t];
    v = *(const float4*)(wemb + (size_t)w * WEDm + c);
  } else {
    int p = posi[t];
    v = *(const float4*)(pemb + (size_t)p * PEDm + (c - WEDm));
  }
  *(float4*)(X + (size_t)t * DIN + c) = v;
}

// ---------------- K2: C = A@W + bias (f32 tiled) ----------------
__global__ __launch_bounds__(256) void k_gemm_bias(const float* __restrict__ A,
    const float* __restrict__ W, const float* __restrict__ bias,
    float* __restrict__ C, int Mm, int Nn, int Kk) {
  __shared__ float As[16][68];
  __shared__ float Bs[16][64];
  int tid = threadIdx.x;
  int tx = tid & 15, ty = tid >> 4;
  int row0 = blockIdx.y * 64, col0 = blockIdx.x * 64;
  float acc[4][4] = {};
  for (int k0 = 0; k0 < Kk; k0 += 16) {
    int r = tid >> 2, c = (tid & 3) * 4;
    float4 av = *(const float4*)(A + (size_t)(row0 + r) * Kk + k0 + c);
    As[c + 0][r] = av.x; As[c + 1][r] = av.y; As[c + 2][r] = av.z; As[c + 3][r] = av.w;
    int r2 = tid >> 4, c2 = (tid & 15) * 4;
    float4 bv = *(const float4*)(W + (size_t)(k0 + r2) * Nn + col0 + c2);
    *(float4*)(&Bs[r2][c2]) = bv;
    __syncthreads();
#pragma unroll
    for (int kk = 0; kk < 16; ++kk) {
      float4 a4 = *(const float4*)(&As[kk][ty * 4]);
      float4 b4 = *(const float4*)(&Bs[kk][tx * 4]);
      float a[4] = {a4.x, a4.y, a4.z, a4.w};
      float b[4] = {b4.x, b4.y, b4.z, b4.w};
#pragma unroll
      for (int i = 0; i < 4; ++i)
#pragma unroll
        for (int j = 0; j < 4; ++j)
          acc[i][j] += a[i] * b[j];
    }
    __syncthreads();
  }
#pragma unroll
  for (int i = 0; i < 4; ++i) {
    int row = row0 + ty * 4 + i;
#pragma unroll
    for (int j = 0; j < 4; ++j) {
      int col = col0 + tx * 4 + j;
      C[(size_t)row * Nn + col] = acc[i][j] + bias[col];
    }
  }
}

// ---------------- DPP helpers ----------------
template <int CTRL>
__device__ __forceinline__ float dpp_add(float x) {
  int xi = __float_as_int(x);
  int yi = __builtin_amdgcn_update_dpp(xi, xi, CTRL, 0xF, 0xF, false);
  return x + __int_as_float(yi);
}

__device__ __forceinline__ float sigm(float x) { return 1.f / (1.f + __expf(-x)); }

// ---------------- K3: LSTM, 64 WGs (32/dir), custom barrier ----------------
// WG w: dir = w>>5, owns units j0 = (w&31)*16 .. +15 (64 gate cols).
// LDS: Whs[64][512] f32 (xor-swizzled k), part[2][64][32] f32.
// Thread map (compute): ks = tid&15 (k-chunk of 32), cq = (tid>>4)&7 (8 cols),
// bq = tid>>7 (8 batches). acc[8][8]. DPP-reduce xor1,xor2,xor8 -> 2 halves in LDS.
// Combine map: u = tid&15, b = tid>>4. c-state in register.
__global__ __launch_bounds__(512, 2) void k_lstm2(
    const float* __restrict__ Whf, const float* __restrict__ Whb,
    const float* __restrict__ GXfp, const float* __restrict__ GXbp,
    const float* __restrict__ maskp, float* __restrict__ Hbuf,
    float* __restrict__ ctx, int* __restrict__ barr) {
  extern __shared__ float lds[];
  float* Whs = lds;                  // 64*512 floats
  float* part = lds + 64 * 512;      // 2*64*32 floats
  int tid = threadIdx.x;
  int wg = blockIdx.x;
  int dir = wg >> 5;
  int j0 = (wg & 31) * 16;
  const float* Wh = dir ? Whb : Whf;
  const float* GX = dir ? GXbp : GXfp;
  int* cnt = barr + dir * 32;        // 128B apart

  // ---- stage Wh slice into LDS (swizzled) ----
  for (int i = tid; i < 8192; i += 512) {
    int c4 = i & 15, k = i >> 4;
    int q = c4 >> 2, u4 = (c4 & 3) * 4;
    float4 v = *(const float4*)(Wh + (size_t)k * G4 + q * HH + j0 + u4);
    int ksw = k ^ (((k >> 5) & 15) << 2);
    int cb = q * 16 + u4;
    Whs[(cb + 0) * 512 + ksw] = v.x;
    Whs[(cb + 1) * 512 + ksw] = v.y;
    Whs[(cb + 2) * 512 + ksw] = v.z;
    Whs[(cb + 3) * 512 + ksw] = v.w;
  }
  // ---- zero h parity-0 for my units ----
  {
    int b = tid >> 4, u = tid & 15;
    Hbuf[(size_t)(0 * 2 + dir) * 16384 + b * 512 + j0 + u] = 0.f;
  }
  __syncthreads();
  if (tid == 0) { __threadfence(); atomicAdd(cnt, 1); }

  const int ks = tid & 15, cq = (tid >> 4) & 7, bq = tid >> 7;
  const int k0 = ks * 32;
  const int ub = tid & 15, bc = tid >> 4;
  float cstate = 0.f;
  long long spins = 0;
  int par = 0;
  for (int s = 0; s < LL; ++s) {
    int t = dir ? (LL - 1 - s) : s;
    if (tid == 0) {
      int target = 32 * (s + 1);
      while (__hip_atomic_load(cnt, __ATOMIC_RELAXED, __HIP_MEMORY_SCOPE_AGENT) < target) {
        if (++spins > 20000000LL) break;   // hang guard
      }
      __threadfence();
    }
    __syncthreads();
    const float* hsrc = Hbuf + (size_t)(par * 2 + dir) * 16384;

    // ---- k-slice matvec: acc[cc][bb] over k in [k0, k0+32) ----
    float acc[8][8];
#pragma unroll
    for (int cc = 0; cc < 8; ++cc)
#pragma unroll
      for (int bb = 0; bb < 8; ++bb) acc[cc][bb] = 0.f;
    const float* hp = hsrc + bq * 8 * 512 + k0;
    const float* wp = Whs + (cq * 8) * 512;
#pragma unroll
    for (int kk = 0; kk < 32; kk += 4) {
      int ksw = (k0 + kk) ^ (ks << 2);
      float4 w4[8], h4[8];
#pragma unroll
      for (int cc = 0; cc < 8; ++cc)
        w4[cc] = *(const float4*)(wp + cc * 512 + ksw);
#pragma unroll
      for (int bb = 0; bb < 8; ++bb)
        h4[bb] = *(const float4*)(hp + bb * 512 + kk);
#pragma unroll
      for (int cc = 0; cc < 8; ++cc) {
        float4 w = w4[cc];
#pragma unroll
        for (int bb = 0; bb < 8; ++bb) {
          float4 h = h4[bb];
          acc[cc][bb] += w.x * h.x + w.y * h.y + w.z * h.z + w.w * h.w;
        }
      }
    }
    // ---- DPP butterfly over ks bits 0,1,3 (xor1, xor2, xor8) ----
#pragma unroll
    for (int cc = 0; cc < 8; ++cc)
#pragma unroll
      for (int bb = 0; bb < 8; ++bb) {
        float v = acc[cc][bb];
        v = dpp_add<0xB1>(v);    // quad_perm xor1
        v = dpp_add<0x4E>(v);    // quad_perm xor2
        v = dpp_add<0x128>(v);   // row_ror:8 == xor8 within row16
        acc[cc][bb] = v;
      }
    // lanes ks==0 hold half-sum over chunks {0-3,8-11}, ks==4 over {4-7,12-15}
    if (ks == 0 || ks == 4) {
      float* dst = part + (ks ? 2048 : 0);
#pragma unroll
      for (int cc = 0; cc < 8; ++cc) {
#pragma unroll
        for (int bt = 0; bt < 2; ++bt) {
          float4 v = make_float4(acc[cc][bt * 4 + 0], acc[cc][bt * 4 + 1],
                                 acc[cc][bt * 4 + 2], acc[cc][bt * 4 + 3]);
          *(float4*)(dst + (cq * 8 + cc) * 32 + bq * 8 + bt * 4) = v;
        }
      }
    }
    __syncthreads();
    // ---- gate combine: thread (u, b) ----
    {
      int u = ub, b = bc;
      float pre[4];
#pragma unroll
      for (int q = 0; q < 4; ++q) {
        int c = q * 16 + u;
        pre[q] = part[c * 32 + b] + part[2048 + c * 32 + b] +
                 GX[((size_t)(b * LL + t)) * G4 + q * HH + j0 + u];
      }
      float gi = sigm(pre[0]);
      float gf = sigm(pre[1]);
      float gg = tanhf(pre[2]);
      float go = sigm(pre[3]);
      float cnew = gf * cstate + gi * gg;
      float hnew = go * tanhf(cnew);
      float m = maskp[b * LL + t];
      float hold = hsrc[b * 512 + j0 + u];
      float hn = hnew * m + hold * (1.f - m);
      cstate = cnew * m + cstate * (1.f - m);
      Hbuf[(size_t)((par ^ 1) * 2 + dir) * 16384 + b * 512 + j0 + u] = hn;
      ctx[((size_t)(b * LL + t)) * (2 * HH) + dir * HH + j0 + u] = hn;
    }
    __syncthreads();
    if (tid == 0) { __threadfence(); atomicAdd(cnt, 1); }
    par ^= 1;
  }
}

__global__ void k_init0(int* __restrict__ barr) { barr[threadIdx.x] = 0; }

// ---------------- K4: tag histogram + stable compaction ----------------
__global__ void k_zero16(int* counts) { if (threadIdx.x < 16) counts[threadIdx.x] = 0; }

__global__ void k_count(const int* __restrict__ posi, int* __restrict__ counts) {
  int t = blockIdx.x * 256 + threadIdx.x;
  if (t < TT) atomicAdd(&counts[posi[t]], 1);
}

__global__ void k_prefix(const int* __restrict__ counts, int* __restrict__ offs) {
  if (threadIdx.x == 0) {
    int a = 0;
    for (int p = 0; p < NTAGS; ++p) { offs[p] = a; a += counts[p]; }
    offs[NTAGS] = a;
  }
}

__global__ __launch_bounds__(256) void k_compact(const int* __restrict__ posi,
    const int* __restrict__ offs, int* __restrict__ idxlist) {
  int p = blockIdx.x, tid = threadIdx.x;
  __shared__ int sc[256];
  __shared__ int sbase;
  if (tid == 0) sbase = offs[p];
  __syncthreads();
  for (int c0 = 0; c0 < TT; c0 += 256) {
    int t = c0 + tid;
    int f = (posi[t] == p) ? 1 : 0;
    int v = f;
    sc[tid] = v;
    __syncthreads();
    for (int o = 1; o < 256; o <<= 1) {
      int add = (tid >= o) ? sc[tid - o] : 0;
      __syncthreads();
      v += add;
      sc[tid] = v;
      __syncthreads();
    }
    int total = sc[255];
    int base = sbase;
    if (f) idxlist[base + v - 1] = t;
    __syncthreads();
    if (tid == 0) sbase = base + total;
    __syncthreads();
  }
}

// ---------------- K4b: gather per-tag psr rows ----------------
__global__ void k_ptbl(const int* __restrict__ wtbl, const float* __restrict__ psrw,
                       float* __restrict__ Ptbl) {
  int i = blockIdx.x * 256 + threadIdx.x;
  int total = NTAGS * MM * EE;
  for (; i < total; i += gridDim.x * 256) {
    int p = i / (MM * EE);
    int rem = i - p * (MM * EE);
    int r = rem / EE;
    int e = rem - r * EE;
    Ptbl[i] = psrw[(size_t)wtbl[p * MM + r] * EE + e];
  }
}

// ---------------- K5: grouped decoder GEMM ----------------
__global__ __launch_bounds__(256) void k_decgemm(const float* __restrict__ ctxb,
    const float* __restrict__ decW, const float* __restrict__ decb,
    const int* __restrict__ counts, const int* __restrict__ offs,
    const int* __restrict__ idxlist, float* __restrict__ Z) {
  int p = blockIdx.z;
  int n = counts[p];
  int r0 = blockIdx.y * 64;
  if (r0 >= n) return;
  int col0 = blockIdx.x * 64;
  __shared__ float As[16][68];
  __shared__ float Bs[16][64];
  __shared__ int rows[64];
  int tid = threadIdx.x;
  if (tid < 64) {
    int r = r0 + tid;
    rows[tid] = idxlist[offs[p] + (r < n ? r : 0)];
  }
  __syncthreads();
  const float* W = decW + (size_t)p * MM * MM;
  float acc[4][4] = {};
  for (int k0 = 0; k0 < MM; k0 += 16) {
    int r = tid >> 2, c = (tid & 3) * 4;
    float4 av = *(const float4*)(ctxb + (size_t)rows[r] * MM + k0 + c);
    As[c + 0][r] = av.x; As[c + 1][r] = av.y; As[c + 2][r] = av.z; As[c + 3][r] = av.w;
    int r2 = tid >> 4, c2 = (tid & 15) * 4;
    float4 bv = *(const float4*)(W + (size_t)(k0 + r2) * MM + col0 + c2);
    *(float4*)(&Bs[r2][c2]) = bv;
    __syncthreads();
#pragma unroll
    for (int kk = 0; kk < 16; ++kk) {
      float4 a4 = *(const float4*)(&As[kk][(tid >> 4) * 4]);
      float4 b4 = *(const float4*)(&Bs[kk][(tid & 15) * 4]);
      float a[4] = {a4.x, a4.y, a4.z, a4.w};
      float b[4] = {b4.x, b4.y, b4.z, b4.w};
#pragma unroll
      for (int i = 0; i < 4; ++i)
#pragma unroll
        for (int j = 0; j < 4; ++j)
          acc[i][j] += a[i] * b[j];
    }
    __syncthreads();
  }
  int tx = tid & 15, ty = tid >> 4;
#pragma unroll
  for (int i = 0; i < 4; ++i) {
    int r = r0 + ty * 4 + i;
    if (r < n) {
      int tok = rows[ty * 4 + i];
#pragma unroll
      for (int j = 0; j < 4; ++j) {
        int col = col0 + tx * 4 + j;
        Z[(size_t)tok * MM + col] = acc[i][j] + decb[p * MM + col];
      }
    }
  }
}

// ---------------- K6: per-token softmax / entropy / gumbel argmax ----------------
__global__ __launch_bounds__(256) void k_softmax(
    const float* __restrict__ Z, const float* __restrict__ gum,
    const int* __restrict__ posi, const int* __restrict__ wflat,
    const int* __restrict__ wtbl, float* __restrict__ SPT,
    float* __restrict__ rowent, int* __restrict__ avoidb,
    float* __restrict__ out_word, float* __restrict__ out_mask,
    float* __restrict__ out_pri) {
  __shared__ float red[256];
  __shared__ float redv[256];
  __shared__ int redi[256];
  int t = blockIdx.x, tid = threadIdx.x;
  float z[4];
#pragma unroll
  for (int i = 0; i < 4; ++i) z[i] = Z[(size_t)t * MM + tid + 256 * i];
  float mx = fmaxf(fmaxf(z[0], z[1]), fmaxf(z[2], z[3]));
  red[tid] = mx; __syncthreads();
  for (int o = 128; o > 0; o >>= 1) { if (tid < o) red[tid] = fmaxf(red[tid], red[tid + o]); __syncthreads(); }
  mx = red[0]; __syncthreads();
  float se = 0.f;
#pragma unroll
  for (int i = 0; i < 4; ++i) se += expf(z[i] - mx);
  red[tid] = se; __syncthreads();
  for (int o = 128; o > 0; o >>= 1) { if (tid < o) red[tid] += red[tid + o]; __syncthreads(); }
  float lse = logf(red[0]); __syncthreads();
  float lp[4]; float ent = 0.f;
#pragma unroll
  for (int i = 0; i < 4; ++i) { lp[i] = z[i] - mx - lse; ent -= lp[i] * expf(lp[i]); }
  red[tid] = ent; __syncthreads();
  for (int o = 128; o > 0; o >>= 1) { if (tid < o) red[tid] += red[tid + o]; __syncthreads(); }
  float enttot = red[0]; __syncthreads();
  float y[4];
#pragma unroll
  for (int i = 0; i < 4; ++i) {
    float u = gum[(size_t)t * MM + tid + 256 * i];
    float g = -logf(-logf(u + 1e-10f) + 1e-10f);
    y[i] = lp[i] + g;
  }
  float bv = y[0]; int bi = tid;
#pragma unroll
  for (int i = 1; i < 4; ++i) { int j = tid + 256 * i; if (y[i] > bv) { bv = y[i]; bi = j; } }
  redv[tid] = bv; redi[tid] = bi; __syncthreads();
  for (int o = 128; o > 0; o >>= 1) {
    if (tid < o) {
      float v2 = redv[tid + o]; int i2 = redi[tid + o];
      if (v2 > redv[tid] || (v2 == redv[tid] && i2 < redi[tid])) { redv[tid] = v2; redi[tid] = i2; }
    }
    __syncthreads();
  }
  float ymax = redv[0]; int amax = redi[0]; __syncthreads();
  float e[4]; float s2 = 0.f;
#pragma unroll
  for (int i = 0; i < 4; ++i) { e[i] = expf(y[i] - ymax); s2 += e[i]; }
  red[tid] = s2; __syncthreads();
  for (int o = 128; o > 0; o >>= 1) { if (tid < o) red[tid] += red[tid + o]; __syncthreads(); }
  float inv = 1.f / red[0];
#pragma unroll
  for (int i = 0; i < 4; ++i) SPT[(size_t)t * MM + tid + 256 * i] = e[i] * inv;
  if (tid == 0) {
    int p = posi[t];
    int widx = wtbl[p * MM + amax];
    int wf = wflat[t];
    int avoid = (widx == wf) ? 1 : 0;
    avoidb[t] = avoid;
    out_word[t] = (float)(avoid ? 0 : widx);
    out_mask[t] = 1.0f;
    out_pri[t] = (p < 4) ? 1.0f : 0.0f;
    rowent[t] = enttot;
  }
}

// ---------------- K7: grouped emb GEMM ----------------
__global__ __launch_bounds__(256) void k_embgemm(const float* __restrict__ SPT,
    const float* __restrict__ Ptbl, const float* __restrict__ psrw,
    const int* __restrict__ counts, const int* __restrict__ offs,
    const int* __restrict__ idxlist, const int* __restrict__ avoidb,
    float* __restrict__ out_emb) {
  int p = blockIdx.y;
  int n = counts[p];
  int r0 = blockIdx.x * 64;
  if (r0 >= n) return;
  __shared__ float As[16][68];
  __shared__ float Bs[16][132];
  __shared__ int rows[64];
  int tid = threadIdx.x;
  if (tid < 64) rows[tid] = idxlist[offs[p] + ((r0 + tid) < n ? (r0 + tid) : 0)];
  __syncthreads();
  const float* P = Ptbl + (size_t)p * MM * EE;
  int tx = tid & 31, ty = tid >> 5;
  float acc[8][4] = {};
  for (int k0 = 0; k0 < MM; k0 += 16) {
    int r = tid >> 2, c = (tid & 3) * 4;
    float4 av = *(const float4*)(SPT + (size_t)rows[r] * MM + k0 + c);
    As[c + 0][r] = av.x; As[c + 1][r] = av.y; As[c + 2][r] = av.z; As[c + 3][r] = av.w;
    int r2 = tid >> 4;
    int c2 = (tid & 15) * 8;
    float4 b0 = make_float4(0.f, 0.f, 0.f, 0.f), b1 = make_float4(0.f, 0.f, 0.f, 0.f);
    if (c2 + 3 < EE) b0 = *(const float4*)(P + (size_t)(k0 + r2) * EE + c2);
    if (c2 + 7 < EE) b1 = *(const float4*)(P + (size_t)(k0 + r2) * EE + c2 + 4);
    *(float4*)(&Bs[r2][c2]) = b0;
    *(float4*)(&Bs[r2][c2 + 4]) = b1;
    __syncthreads();
#pragma unroll
    for (int kk = 0; kk < 16; ++kk) {
      float4 b4 = *(const float4*)(&Bs[kk][tx * 4]);
      float4 a0 = *(const float4*)(&As[kk][ty * 8]);
      float4 a1 = *(const float4*)(&As[kk][ty * 8 + 4]);
      float a[8] = {a0.x, a0.y, a0.z, a0.w, a1.x, a1.y, a1.z, a1.w};
#pragma unroll
      for (int ri = 0; ri < 8; ++ri) {
        acc[ri][0] += a[ri] * b4.x; acc[ri][1] += a[ri] * b4.y;
        acc[ri][2] += a[ri] * b4.z; acc[ri][3] += a[ri] * b4.w;
      }
    }
    __syncthreads();
  }
#pragma unroll
  for (int ri = 0; ri < 8; ++ri) {
    int r = ty * 8 + ri;
    if (r0 + r < n) {
      int tok = rows[r];
      int av = avoidb[tok];
#pragma unroll
      for (int j = 0; j < 4; ++j) {
        int col = tx * 4 + j;
        if (col < EE) {
          float v = av ? psrw[col] : acc[ri][j];
          out_emb[(size_t)tok * EE + col] = v;
        }
      }
    }
  }
}

// ---------------- K8: deterministic entropy-loss reduction ----------------
__global__ __launch_bounds__(256) void k_final(const float* __restrict__ rowent,
    const int* __restrict__ posi, const int* __restrict__ counts,
    float* __restrict__ out_loss) {
  __shared__ float red[256];
  int tid = threadIdx.x;
  float s = 0.f;
  for (int t = tid; t < TT; t += 256) {
    int p = posi[t];
    float denom = fmaxf((float)counts[p] * (float)MM, 1.0f);
    s += rowent[t] / denom;
  }
  red[tid] = s; __syncthreads();
  for (int o = 128; o > 0; o >>= 1) { if (tid < o) red[tid] += red[tid + o]; __syncthreads(); }
  if (tid == 0) out_loss[0] = -red[0] * 0.01f;
}

// ---------------- launcher ----------------
extern "C" void kernel_launch(void* const* d_in, const int* in_sizes, int n_in,
                              void* d_out, int out_size, void* d_ws, size_t ws_size,
                              hipStream_t stream) {
  const int*   inp_word = (const int*)d_in[0];
  const int*   inp_pos  = (const int*)d_in[1];
  const float* inp_mask = (const float*)d_in[2];
  const float* gum      = (const float*)d_in[3];
  const float* wemb     = (const float*)d_in[4];
  const float* pemb     = (const float*)d_in[5];
  const float* Wx_f     = (const float*)d_in[6];
  const float* Wh_f     = (const float*)d_in[7];
  const float* b_f      = (const float*)d_in[8];
  const float* Wx_b     = (const float*)d_in[9];
  const float* Wh_b     = (const float*)d_in[10];
  const float* b_b      = (const float*)d_in[11];
  const float* decW     = (const float*)d_in[12];
  const float* decb     = (const float*)d_in[13];
  const int*   wtbl     = (const int*)d_in[14];
  const float* psrw     = (const float*)d_in[15];

  float* out_word = (float*)d_out;
  float* out_emb  = out_word + TT;
  float* out_mask = out_emb + (size_t)TT * EE;
  float* out_pri  = out_mask + TT;
  float* out_loss = out_pri + TT;

  float* ws = (float*)d_ws;
  float* X      = ws;
  float* GXf    = X + (size_t)TT * DIN;
  float* GXb    = GXf + (size_t)TT * G4;
  float* ctxb   = GXb + (size_t)TT * G4;
  float* Hbuf   = ctxb + (size_t)TT * MM;
  float* rowent = Hbuf + 2 * 2 * BB * HH;
  int* avoidb   = (int*)(rowent + TT);
  int* counts   = avoidb + TT;
  int* offs     = counts + 16;
  int* idxlist  = offs + 32;
  int* barr     = idxlist + TT;
  float* Z    = GXf;   // reuse: GX dead after LSTM
  float* SPT  = Z;     // in-place row rewrite in k_softmax
  float* Ptbl = GXb;   // reuse

  k_embed<<<TT, 64, 0, stream>>>(inp_word, inp_pos, wemb, pemb, X);
  k_gemm_bias<<<dim3(G4 / 64, TT / 64), 256, 0, stream>>>(X, Wx_f, b_f, GXf, TT, G4, DIN);
  k_gemm_bias<<<dim3(G4 / 64, TT / 64), 256, 0, stream>>>(X, Wx_b, b_b, GXb, TT, G4, DIN);

  k_init0<<<1, 64, 0, stream>>>(barr);
  {
    const int ldsz = (64 * 512 + 2 * 64 * 32) * 4;  // 147456 B
    static bool attr_done = false;
    hipFuncSetAttribute((const void*)k_lstm2,
                        hipFuncAttributeMaxDynamicSharedMemorySize, ldsz);
    (void)attr_done;
    k_lstm2<<<64, 512, ldsz, stream>>>(Wh_f, Wh_b, GXf, GXb, inp_mask, Hbuf, ctxb, barr);
  }

  k_zero16<<<1, 64, 0, stream>>>(counts);
  k_count<<<TT / 256, 256, 0, stream>>>(inp_pos, counts);
  k_prefix<<<1, 64, 0, stream>>>(counts, offs);
  k_compact<<<NTAGS, 256, 0, stream>>>(inp_pos, offs, idxlist);
  k_ptbl<<<1024, 256, 0, stream>>>(wtbl, psrw, Ptbl);
  k_decgemm<<<dim3(MM / 64, TT / 64, NTAGS), 256, 0, stream>>>(ctxb, decW, decb, counts, offs, idxlist, Z);
  k_softmax<<<TT, 256, 0, stream>>>(Z, gum, inp_pos, inp_word, wtbl, SPT, rowent, avoidb,
                                    out_word, out_mask, out_pri);
  k_embgemm<<<dim3(TT / 64, NTAGS), 256, 0, stream>>>(SPT, Ptbl, psrw, counts, offs, idxlist,
                                                      avoidb, out_emb);
  k_final<<<1, 256, 0, stream>>>(rowent, inp_pos, counts, out_loss);
}

// Round 3
// 4212.060 us; speedup vs baseline: 6.4981x; 6.4981x over previous
//
#include <hip/hip_runtime.h>
#include <math.h>
#include <cstdint>

#define BB 32
#define LL 256
#define TT 8192     // B*L
#define DIN 256
#define WEDm 200
#define PEDm 56
#define HH 512
#define G4 2048
#define MM 1024
#define EE 100
#define NTAGS 16

// ---------------- K1: embedding concat ----------------
__global__ void k_embed(const int* __restrict__ word, const int* __restrict__ posi,
                        const float* __restrict__ wemb, const float* __restrict__ pemb,
                        float* __restrict__ X) {
  int t = blockIdx.x;
  int c = threadIdx.x * 4;
  float4 v;
  if (c < WEDm) {
    int w = word[t];
    v = *(const float4*)(wemb + (size_t)w * WEDm + c);
  } else {
    int p = posi[t];
    v = *(const float4*)(pemb + (size_t)p * PEDm + (c - WEDm));
  }
  *(float4*)(X + (size_t)t * DIN + c) = v;
}

// ---------------- K2: C = A@W + bias (f32 tiled) ----------------
__global__ __launch_bounds__(256) void k_gemm_bias(const float* __restrict__ A,
    const float* __restrict__ W, const float* __restrict__ bias,
    float* __restrict__ C, int Mm, int Nn, int Kk) {
  __shared__ float As[16][68];
  __shared__ float Bs[16][64];
  int tid = threadIdx.x;
  int tx = tid & 15, ty = tid >> 4;
  int row0 = blockIdx.y * 64, col0 = blockIdx.x * 64;
  float acc[4][4] = {};
  for (int k0 = 0; k0 < Kk; k0 += 16) {
    int r = tid >> 2, c = (tid & 3) * 4;
    float4 av = *(const float4*)(A + (size_t)(row0 + r) * Kk + k0 + c);
    As[c + 0][r] = av.x; As[c + 1][r] = av.y; As[c + 2][r] = av.z; As[c + 3][r] = av.w;
    int r2 = tid >> 4, c2 = (tid & 15) * 4;
    float4 bv = *(const float4*)(W + (size_t)(k0 + r2) * Nn + col0 + c2);
    *(float4*)(&Bs[r2][c2]) = bv;
    __syncthreads();
#pragma unroll
    for (int kk = 0; kk < 16; ++kk) {
      float4 a4 = *(const float4*)(&As[kk][ty * 4]);
      float4 b4 = *(const float4*)(&Bs[kk][tx * 4]);
      float a[4] = {a4.x, a4.y, a4.z, a4.w};
      float b[4] = {b4.x, b4.y, b4.z, b4.w};
#pragma unroll
      for (int i = 0; i < 4; ++i)
#pragma unroll
        for (int j = 0; j < 4; ++j)
          acc[i][j] += a[i] * b[j];
    }
    __syncthreads();
  }
#pragma unroll
  for (int i = 0; i < 4; ++i) {
    int row = row0 + ty * 4 + i;
#pragma unroll
    for (int j = 0; j < 4; ++j) {
      int col = col0 + tx * 4 + j;
      C[(size_t)row * Nn + col] = acc[i][j] + bias[col];
    }
  }
}

// ---------------- DPP helper: rotate-add within row16 ----------------
template <int N>
__device__ __forceinline__ float ror_add(float x) {
  int xi = __float_as_int(x);
  int yi = __builtin_amdgcn_update_dpp(xi, xi, 0x100 + N, 0xF, 0xF, false);
  return x + __int_as_float(yi);
}

__device__ __forceinline__ float sigm(float x) { return 1.f / (1.f + __expf(-x)); }

// ---------------- K3: LSTM, 128 WGs (64/dir, 8 units each), fence-free ----------------
// All cross-WG h traffic via RELAXED agent-scope atomics (sc1 -> MALL, no cache flush).
// Ordering: data stores -> s_waitcnt vmcnt(0) -> flag add. Spin on relaxed flag load.
__global__ __launch_bounds__(512, 1) void k_lstm3(
    const float* __restrict__ Whf, const float* __restrict__ Whb,
    const float* __restrict__ GXfp, const float* __restrict__ GXbp,
    const float* __restrict__ maskp, float* __restrict__ Hbuf,
    float* __restrict__ ctx, int* __restrict__ flags) {
  extern __shared__ float lds[];
  float* Whs  = lds;                    // [32 gate-cols][512]
  float* Hs   = lds + 16384;            // [32 b][516]
  float* part = lds + 16384 + 16512;    // [2][32 gc][36]
  const int tid = threadIdx.x;
  const int wg  = blockIdx.x;
  const int dir = wg >> 6;
  const int j0  = (wg & 63) * 8;        // 8 hidden units per WG
  const float* Wh = dir ? Whb : Whf;
  const float* GX = dir ? GXbp : GXfp;
  int* cnt = flags + dir * 64;          // 256B apart

  // ---- stage Wh slice: Whs[c][k], c = q*8+u  (gcol = q*512 + j0 + u) ----
  for (int i = tid; i < 32 * 512; i += 512) {
    int c = i >> 9, k = i & 511;
    int q = c >> 3, u = c & 7;
    Whs[c * 512 + k] = Wh[(size_t)k * G4 + q * HH + j0 + u];
  }
  // ---- zero my h slice (parity 0) via relaxed agent stores ----
  if (tid < 256) {
    int u = tid & 7, b = tid >> 3;
    __hip_atomic_store(&Hbuf[(size_t)(0 * 2 + dir) * 16384 + b * HH + j0 + u], 0.f,
                       __ATOMIC_RELAXED, __HIP_MEMORY_SCOPE_AGENT);
  }
  asm volatile("s_waitcnt vmcnt(0)" ::: "memory");
  __syncthreads();
  if (tid == 0)
    __hip_atomic_fetch_add(cnt, 1, __ATOMIC_RELAXED, __HIP_MEMORY_SCOPE_AGENT);

  const int ks = tid & 31;
  const int cq = (tid >> 5) & 3;
  const int bq = (tid >> 7) & 3;
  const int uu = tid & 7, bb = tid >> 3;   // combine map (tid<256)
  float cstate = 0.f;
  int par = 0;

  for (int s = 0; s < LL; ++s) {
    const int t = dir ? (LL - 1 - s) : s;

    // ---- prefetch GX + mask (plain cached loads, independent of h) ----
    float gx0 = 0.f, gx1 = 0.f, gx2 = 0.f, gx3 = 0.f, mval = 0.f;
    if (tid < 256) {
      const float* gp = GX + ((size_t)(bb * LL + t)) * G4 + j0 + uu;
      gx0 = gp[0]; gx1 = gp[512]; gx2 = gp[1024]; gx3 = gp[1536];
      mval = maskp[bb * LL + t];
    }

    // ---- wait for all WGs of my dir to finish step s-1 ----
    if (tid == 0) {
      int target = 64 * (s + 1);
      int it = 0;
      while (__hip_atomic_load(cnt, __ATOMIC_RELAXED, __HIP_MEMORY_SCOPE_AGENT) < target) {
        __builtin_amdgcn_s_sleep(2);
        if (++it > (1 << 18)) break;   // hang guard
      }
    }
    __syncthreads();
    __builtin_amdgcn_sched_barrier(0);

    // ---- load h[par] (64KB) via relaxed agent 8B loads; stage to LDS ----
    {
      const unsigned long long* hb64 =
          (const unsigned long long*)(Hbuf + (size_t)(par * 2 + dir) * 16384);
      unsigned long long hv[16];
#pragma unroll
      for (int m = 0; m < 16; ++m)
        hv[m] = __hip_atomic_load(&hb64[tid + 512 * m], __ATOMIC_RELAXED,
                                  __HIP_MEMORY_SCOPE_AGENT);
#pragma unroll
      for (int m = 0; m < 16; ++m) {
        int f = 2 * (tid + 512 * m);
        int b = f >> 9, k = f & 511;
        *(float2*)(&Hs[b * 516 + k]) = *(float2*)(&hv[m]);
      }
    }
    __syncthreads();

    // ---- 8x8 register-tiled matvec, lane-strided k (conflict-free b128) ----
    float acc[8][8];
#pragma unroll
    for (int ci = 0; ci < 8; ++ci)
#pragma unroll
      for (int bi = 0; bi < 8; ++bi) acc[ci][bi] = 0.f;
    {
      const float* wp = Whs + (cq * 8) * 512 + 4 * ks;
      const float* hp = Hs + (bq * 8) * 516 + 4 * ks;
#pragma unroll
      for (int j = 0; j < 4; ++j) {
        const int ko = 128 * j;
        float4 w4[8], h4[8];
#pragma unroll
        for (int ci = 0; ci < 8; ++ci) w4[ci] = *(const float4*)(wp + ci * 512 + ko);
#pragma unroll
        for (int bi = 0; bi < 8; ++bi) h4[bi] = *(const float4*)(hp + bi * 516 + ko);
#pragma unroll
        for (int ci = 0; ci < 8; ++ci) {
          float4 w = w4[ci];
#pragma unroll
          for (int bi = 0; bi < 8; ++bi) {
            float4 h = h4[bi];
            acc[ci][bi] += w.x * h.x + w.y * h.y + w.z * h.z + w.w * h.w;
          }
        }
      }
    }
    // ---- reduce over ks within row16 (ror-allreduce), 2 partials ----
#pragma unroll
    for (int ci = 0; ci < 8; ++ci)
#pragma unroll
      for (int bi = 0; bi < 8; ++bi) {
        float v = acc[ci][bi];
        v = ror_add<1>(v); v = ror_add<2>(v); v = ror_add<4>(v); v = ror_add<8>(v);
        acc[ci][bi] = v;
      }
    if ((ks & 15) == 0) {
      const int ph = ks >> 4;
      float* dst = part + ph * 1152 + (cq * 8) * 36 + bq * 8;
#pragma unroll
      for (int ci = 0; ci < 8; ++ci) {
        *(float4*)(dst + ci * 36 + 0) = make_float4(acc[ci][0], acc[ci][1], acc[ci][2], acc[ci][3]);
        *(float4*)(dst + ci * 36 + 4) = make_float4(acc[ci][4], acc[ci][5], acc[ci][6], acc[ci][7]);
      }
    }
    __syncthreads();

    // ---- gate combine (tid<256): unit uu, batch bb ----
    if (tid < 256) {
      float pre[4];
#pragma unroll
      for (int q = 0; q < 4; ++q) {
        int c = q * 8 + uu;
        pre[q] = part[c * 36 + bb] + part[1152 + c * 36 + bb];
      }
      pre[0] += gx0; pre[1] += gx1; pre[2] += gx2; pre[3] += gx3;
      float gi = sigm(pre[0]);
      float gf = sigm(pre[1]);
      float gg = tanhf(pre[2]);
      float go = sigm(pre[3]);
      float cnew = gf * cstate + gi * gg;
      float hnew = go * tanhf(cnew);
      float hold = Hs[bb * 516 + j0 + uu];
      float hn = hnew * mval + hold * (1.f - mval);
      cstate = cnew * mval + cstate * (1.f - mval);
      __hip_atomic_store(&Hbuf[(size_t)((par ^ 1) * 2 + dir) * 16384 + bb * HH + j0 + uu],
                         hn, __ATOMIC_RELAXED, __HIP_MEMORY_SCOPE_AGENT);
      ctx[((size_t)(bb * LL + t)) * (2 * HH) + dir * HH + j0 + uu] = hn;
    }
    asm volatile("s_waitcnt vmcnt(0)" ::: "memory");
    __syncthreads();
    if (tid == 0)
      __hip_atomic_fetch_add(cnt, 1, __ATOMIC_RELAXED, __HIP_MEMORY_SCOPE_AGENT);
    par ^= 1;
  }
}

__global__ void k_init0(int* __restrict__ flags) { flags[threadIdx.x] = 0; }

// ---------------- K4: tag histogram + stable compaction ----------------
__global__ void k_zero16(int* counts) { if (threadIdx.x < 16) counts[threadIdx.x] = 0; }

__global__ void k_count(const int* __restrict__ posi, int* __restrict__ counts) {
  int t = blockIdx.x * 256 + threadIdx.x;
  if (t < TT) atomicAdd(&counts[posi[t]], 1);
}

__global__ void k_prefix(const int* __restrict__ counts, int* __restrict__ offs) {
  if (threadIdx.x == 0) {
    int a = 0;
    for (int p = 0; p < NTAGS; ++p) { offs[p] = a; a += counts[p]; }
    offs[NTAGS] = a;
  }
}

__global__ __launch_bounds__(256) void k_compact(const int* __restrict__ posi,
    const int* __restrict__ offs, int* __restrict__ idxlist) {
  int p = blockIdx.x, tid = threadIdx.x;
  __shared__ int sc[256];
  __shared__ int sbase;
  if (tid == 0) sbase = offs[p];
  __syncthreads();
  for (int c0 = 0; c0 < TT; c0 += 256) {
    int t = c0 + tid;
    int f = (posi[t] == p) ? 1 : 0;
    int v = f;
    sc[tid] = v;
    __syncthreads();
    for (int o = 1; o < 256; o <<= 1) {
      int add = (tid >= o) ? sc[tid - o] : 0;
      __syncthreads();
      v += add;
      sc[tid] = v;
      __syncthreads();
    }
    int total = sc[255];
    int base = sbase;
    if (f) idxlist[base + v - 1] = t;
    __syncthreads();
    if (tid == 0) sbase = base + total;
    __syncthreads();
  }
}

// ---------------- K4b: gather per-tag psr rows ----------------
__global__ void k_ptbl(const int* __restrict__ wtbl, const float* __restrict__ psrw,
                       float* __restrict__ Ptbl) {
  int i = blockIdx.x * 256 + threadIdx.x;
  int total = NTAGS * MM * EE;
  for (; i < total; i += gridDim.x * 256) {
    int p = i / (MM * EE);
    int rem = i - p * (MM * EE);
    int r = rem / EE;
    int e = rem - r * EE;
    Ptbl[i] = psrw[(size_t)wtbl[p * MM + r] * EE + e];
  }
}

// ---------------- K5: grouped decoder GEMM ----------------
__global__ __launch_bounds__(256) void k_decgemm(const float* __restrict__ ctxb,
    const float* __restrict__ decW, const float* __restrict__ decb,
    const int* __restrict__ counts, const int* __restrict__ offs,
    const int* __restrict__ idxlist, float* __restrict__ Z) {
  int p = blockIdx.z;
  int n = counts[p];
  int r0 = blockIdx.y * 64;
  if (r0 >= n) return;
  int col0 = blockIdx.x * 64;
  __shared__ float As[16][68];
  __shared__ float Bs[16][64];
  __shared__ int rows[64];
  int tid = threadIdx.x;
  if (tid < 64) {
    int r = r0 + tid;
    rows[tid] = idxlist[offs[p] + (r < n ? r : 0)];
  }
  __syncthreads();
  const float* W = decW + (size_t)p * MM * MM;
  float acc[4][4] = {};
  for (int k0 = 0; k0 < MM; k0 += 16) {
    int r = tid >> 2, c = (tid & 3) * 4;
    float4 av = *(const float4*)(ctxb + (size_t)rows[r] * MM + k0 + c);
    As[c + 0][r] = av.x; As[c + 1][r] = av.y; As[c + 2][r] = av.z; As[c + 3][r] = av.w;
    int r2 = tid >> 4, c2 = (tid & 15) * 4;
    float4 bv = *(const float4*)(W + (size_t)(k0 + r2) * MM + col0 + c2);
    *(float4*)(&Bs[r2][c2]) = bv;
    __syncthreads();
#pragma unroll
    for (int kk = 0; kk < 16; ++kk) {
      float4 a4 = *(const float4*)(&As[kk][(tid >> 4) * 4]);
      float4 b4 = *(const float4*)(&Bs[kk][(tid & 15) * 4]);
      float a[4] = {a4.x, a4.y, a4.z, a4.w};
      float b[4] = {b4.x, b4.y, b4.z, b4.w};
#pragma unroll
      for (int i = 0; i < 4; ++i)
#pragma unroll
        for (int j = 0; j < 4; ++j)
          acc[i][j] += a[i] * b[j];
    }
    __syncthreads();
  }
  int tx = tid & 15, ty = tid >> 4;
#pragma unroll
  for (int i = 0; i < 4; ++i) {
    int r = r0 + ty * 4 + i;
    if (r < n) {
      int tok = rows[ty * 4 + i];
#pragma unroll
      for (int j = 0; j < 4; ++j) {
        int col = col0 + tx * 4 + j;
        Z[(size_t)tok * MM + col] = acc[i][j] + decb[p * MM + col];
      }
    }
  }
}

// ---------------- K6: per-token softmax / entropy / gumbel argmax ----------------
__global__ __launch_bounds__(256) void k_softmax(
    const float* __restrict__ Z, const float* __restrict__ gum,
    const int* __restrict__ posi, const int* __restrict__ wflat,
    const int* __restrict__ wtbl, float* __restrict__ SPT,
    float* __restrict__ rowent, int* __restrict__ avoidb,
    float* __restrict__ out_word, float* __restrict__ out_mask,
    float* __restrict__ out_pri) {
  __shared__ float red[256];
  __shared__ float redv[256];
  __shared__ int redi[256];
  int t = blockIdx.x, tid = threadIdx.x;
  float z[4];
#pragma unroll
  for (int i = 0; i < 4; ++i) z[i] = Z[(size_t)t * MM + tid + 256 * i];
  float mx = fmaxf(fmaxf(z[0], z[1]), fmaxf(z[2], z[3]));
  red[tid] = mx; __syncthreads();
  for (int o = 128; o > 0; o >>= 1) { if (tid < o) red[tid] = fmaxf(red[tid], red[tid + o]); __syncthreads(); }
  mx = red[0]; __syncthreads();
  float se = 0.f;
#pragma unroll
  for (int i = 0; i < 4; ++i) se += expf(z[i] - mx);
  red[tid] = se; __syncthreads();
  for (int o = 128; o > 0; o >>= 1) { if (tid < o) red[tid] += red[tid + o]; __syncthreads(); }
  float lse = logf(red[0]); __syncthreads();
  float lp[4]; float ent = 0.f;
#pragma unroll
  for (int i = 0; i < 4; ++i) { lp[i] = z[i] - mx - lse; ent -= lp[i] * expf(lp[i]); }
  red[tid] = ent; __syncthreads();
  for (int o = 128; o > 0; o >>= 1) { if (tid < o) red[tid] += red[tid + o]; __syncthreads(); }
  float enttot = red[0]; __syncthreads();
  float y[4];
#pragma unroll
  for (int i = 0; i < 4; ++i) {
    float u = gum[(size_t)t * MM + tid + 256 * i];
    float g = -logf(-logf(u + 1e-10f) + 1e-10f);
    y[i] = lp[i] + g;
  }
  float bv = y[0]; int bi = tid;
#pragma unroll
  for (int i = 1; i < 4; ++i) { int j = tid + 256 * i; if (y[i] > bv) { bv = y[i]; bi = j; } }
  redv[tid] = bv; redi[tid] = bi; __syncthreads();
  for (int o = 128; o > 0; o >>= 1) {
    if (tid < o) {
      float v2 = redv[tid + o]; int i2 = redi[tid + o];
      if (v2 > redv[tid] || (v2 == redv[tid] && i2 < redi[tid])) { redv[tid] = v2; redi[tid] = i2; }
    }
    __syncthreads();
  }
  float ymax = redv[0]; int amax = redi[0]; __syncthreads();
  float e[4]; float s2 = 0.f;
#pragma unroll
  for (int i = 0; i < 4; ++i) { e[i] = expf(y[i] - ymax); s2 += e[i]; }
  red[tid] = s2; __syncthreads();
  for (int o = 128; o > 0; o >>= 1) { if (tid < o) red[tid] += red[tid + o]; __syncthreads(); }
  float inv = 1.f / red[0];
#pragma unroll
  for (int i = 0; i < 4; ++i) SPT[(size_t)t * MM + tid + 256 * i] = e[i] * inv;
  if (tid == 0) {
    int p = posi[t];
    int widx = wtbl[p * MM + amax];
    int wf = wflat[t];
    int avoid = (widx == wf) ? 1 : 0;
    avoidb[t] = avoid;
    out_word[t] = (float)(avoid ? 0 : widx);
    out_mask[t] = 1.0f;
    out_pri[t] = (p < 4) ? 1.0f : 0.0f;
    rowent[t] = enttot;
  }
}

// ---------------- K7: grouped emb GEMM ----------------
__global__ __launch_bounds__(256) void k_embgemm(const float* __restrict__ SPT,
    const float* __restrict__ Ptbl, const float* __restrict__ psrw,
    const int* __restrict__ counts, const int* __restrict__ offs,
    const int* __restrict__ idxlist, const int* __restrict__ avoidb,
    float* __restrict__ out_emb) {
  int p = blockIdx.y;
  int n = counts[p];
  int r0 = blockIdx.x * 64;
  if (r0 >= n) return;
  __shared__ float As[16][68];
  __shared__ float Bs[16][132];
  __shared__ int rows[64];
  int tid = threadIdx.x;
  if (tid < 64) rows[tid] = idxlist[offs[p] + ((r0 + tid) < n ? (r0 + tid) : 0)];
  __syncthreads();
  const float* P = Ptbl + (size_t)p * MM * EE;
  int tx = tid & 31, ty = tid >> 5;
  float acc[8][4] = {};
  for (int k0 = 0; k0 < MM; k0 += 16) {
    int r = tid >> 2, c = (tid & 3) * 4;
    float4 av = *(const float4*)(SPT + (size_t)rows[r] * MM + k0 + c);
    As[c + 0][r] = av.x; As[c + 1][r] = av.y; As[c + 2][r] = av.z; As[c + 3][r] = av.w;
    int r2 = tid >> 4;
    int c2 = (tid & 15) * 8;
    float4 b0 = make_float4(0.f, 0.f, 0.f, 0.f), b1 = make_float4(0.f, 0.f, 0.f, 0.f);
    if (c2 + 3 < EE) b0 = *(const float4*)(P + (size_t)(k0 + r2) * EE + c2);
    if (c2 + 7 < EE) b1 = *(const float4*)(P + (size_t)(k0 + r2) * EE + c2 + 4);
    *(float4*)(&Bs[r2][c2]) = b0;
    *(float4*)(&Bs[r2][c2 + 4]) = b1;
    __syncthreads();
#pragma unroll
    for (int kk = 0; kk < 16; ++kk) {
      float4 b4 = *(const float4*)(&Bs[kk][tx * 4]);
      float4 a0 = *(const float4*)(&As[kk][ty * 8]);
      float4 a1 = *(const float4*)(&As[kk][ty * 8 + 4]);
      float a[8] = {a0.x, a0.y, a0.z, a0.w, a1.x, a1.y, a1.z, a1.w};
#pragma unroll
      for (int ri = 0; ri < 8; ++ri) {
        acc[ri][0] += a[ri] * b4.x; acc[ri][1] += a[ri] * b4.y;
        acc[ri][2] += a[ri] * b4.z; acc[ri][3] += a[ri] * b4.w;
      }
    }
    __syncthreads();
  }
#pragma unroll
  for (int ri = 0; ri < 8; ++ri) {
    int r = ty * 8 + ri;
    if (r0 + r < n) {
      int tok = rows[r];
      int av = avoidb[tok];
#pragma unroll
      for (int j = 0; j < 4; ++j) {
        int col = tx * 4 + j;
        if (col < EE) {
          float v = av ? psrw[col] : acc[ri][j];
          out_emb[(size_t)tok * EE + col] = v;
        }
      }
    }
  }
}

// ---------------- K8: deterministic entropy-loss reduction ----------------
__global__ __launch_bounds__(256) void k_final(const float* __restrict__ rowent,
    const int* __restrict__ posi, const int* __restrict__ counts,
    float* __restrict__ out_loss) {
  __shared__ float red[256];
  int tid = threadIdx.x;
  float s = 0.f;
  for (int t = tid; t < TT; t += 256) {
    int p = posi[t];
    float denom = fmaxf((float)counts[p] * (float)MM, 1.0f);
    s += rowent[t] / denom;
  }
  red[tid] = s; __syncthreads();
  for (int o = 128; o > 0; o >>= 1) { if (tid < o) red[tid] += red[tid + o]; __syncthreads(); }
  if (tid == 0) out_loss[0] = -red[0] * 0.01f;
}

// ---------------- launcher ----------------
extern "C" void kernel_launch(void* const* d_in, const int* in_sizes, int n_in,
                              void* d_out, int out_size, void* d_ws, size_t ws_size,
                              hipStream_t stream) {
  const int*   inp_word = (const int*)d_in[0];
  const int*   inp_pos  = (const int*)d_in[1];
  const float* inp_mask = (const float*)d_in[2];
  const float* gum      = (const float*)d_in[3];
  const float* wemb     = (const float*)d_in[4];
  const float* pemb     = (const float*)d_in[5];
  const float* Wx_f     = (const float*)d_in[6];
  const float* Wh_f     = (const float*)d_in[7];
  const float* b_f      = (const float*)d_in[8];
  const float* Wx_b     = (const float*)d_in[9];
  const float* Wh_b     = (const float*)d_in[10];
  const float* b_b      = (const float*)d_in[11];
  const float* decW     = (const float*)d_in[12];
  const float* decb     = (const float*)d_in[13];
  const int*   wtbl     = (const int*)d_in[14];
  const float* psrw     = (const float*)d_in[15];

  float* out_word = (float*)d_out;
  float* out_emb  = out_word + TT;
  float* out_mask = out_emb + (size_t)TT * EE;
  float* out_pri  = out_mask + TT;
  float* out_loss = out_pri + TT;

  float* ws = (float*)d_ws;
  float* X      = ws;
  float* GXf    = X + (size_t)TT * DIN;
  float* GXb    = GXf + (size_t)TT * G4;
  float* ctxb   = GXb + (size_t)TT * G4;
  float* Hbuf   = ctxb + (size_t)TT * MM;
  float* rowent = Hbuf + 2 * 2 * BB * HH;
  int* avoidb   = (int*)(rowent + TT);
  int* counts   = avoidb + TT;
  int* offs     = counts + 16;
  int* idxlist  = offs + 32;
  int* flags    = idxlist + TT;
  float* Z    = GXf;   // reuse: GX dead after LSTM
  float* SPT  = Z;     // in-place row rewrite in k_softmax
  float* Ptbl = GXb;   // reuse

  k_embed<<<TT, 64, 0, stream>>>(inp_word, inp_pos, wemb, pemb, X);
  k_gemm_bias<<<dim3(G4 / 64, TT / 64), 256, 0, stream>>>(X, Wx_f, b_f, GXf, TT, G4, DIN);
  k_gemm_bias<<<dim3(G4 / 64, TT / 64), 256, 0, stream>>>(X, Wx_b, b_b, GXb, TT, G4, DIN);

  k_init0<<<1, 128, 0, stream>>>(flags);
  {
    const int ldsz = (16384 + 16512 + 2304) * 4;  // 140800 B
    hipFuncSetAttribute((const void*)k_lstm3,
                        hipFuncAttributeMaxDynamicSharedMemorySize, ldsz);
    k_lstm3<<<128, 512, ldsz, stream>>>(Wh_f, Wh_b, GXf, GXb, inp_mask, Hbuf, ctxb, flags);
  }

  k_zero16<<<1, 64, 0, stream>>>(counts);
  k_count<<<TT / 256, 256, 0, stream>>>(inp_pos, counts);
  k_prefix<<<1, 64, 0, stream>>>(counts, offs);
  k_compact<<<NTAGS, 256, 0, stream>>>(inp_pos, offs, idxlist);
  k_ptbl<<<1024, 256, 0, stream>>>(wtbl, psrw, Ptbl);
  k_decgemm<<<dim3(MM / 64, TT / 64, NTAGS), 256, 0, stream>>>(ctxb, decW, decb, counts, offs, idxlist, Z);
  k_softmax<<<TT, 256, 0, stream>>>(Z, gum, inp_pos, inp_word, wtbl, SPT, rowent, avoidb,
                                    out_word, out_mask, out_pri);
  k_embgemm<<<dim3(TT / 64, NTAGS), 256, 0, stream>>>(SPT, Ptbl, psrw, counts, offs, idxlist,
                                                      avoidb, out_emb);
  k_final<<<1, 256, 0, stream>>>(rowent, inp_pos, counts, out_loss);
}

// Round 4
// 2751.546 us; speedup vs baseline: 9.9472x; 1.5308x over previous
//
#include <hip/hip_runtime.h>
#include <math.h>
#include <cstdint>

#define BB 32
#define LL 256
#define TT 8192     // B*L
#define DIN 256
#define WEDm 200
#define PEDm 56
#define HH 512
#define G4 2048
#define MM 1024
#define EE 100
#define NTAGS 16

// ---------------- K1: embedding concat ----------------
__global__ void k_embed(const int* __restrict__ word, const int* __restrict__ posi,
                        const float* __restrict__ wemb, const float* __restrict__ pemb,
                        float* __restrict__ X) {
  int t = blockIdx.x;
  int c = threadIdx.x * 4;
  float4 v;
  if (c < WEDm) {
    int w = word[t];
    v = *(const float4*)(wemb + (size_t)w * WEDm + c);
  } else {
    int p = posi[t];
    v = *(const float4*)(pemb + (size_t)p * PEDm + (c - WEDm));
  }
  *(float4*)(X + (size_t)t * DIN + c) = v;
}

// ---------------- K2: C = A@W + bias (f32 tiled) ----------------
__global__ __launch_bounds__(256) void k_gemm_bias(const float* __restrict__ A,
    const float* __restrict__ W, const float* __restrict__ bias,
    float* __restrict__ C, int Mm, int Nn, int Kk) {
  __shared__ float As[16][68];
  __shared__ float Bs[16][64];
  int tid = threadIdx.x;
  int tx = tid & 15, ty = tid >> 4;
  int row0 = blockIdx.y * 64, col0 = blockIdx.x * 64;
  float acc[4][4] = {};
  for (int k0 = 0; k0 < Kk; k0 += 16) {
    int r = tid >> 2, c = (tid & 3) * 4;
    float4 av = *(const float4*)(A + (size_t)(row0 + r) * Kk + k0 + c);
    As[c + 0][r] = av.x; As[c + 1][r] = av.y; As[c + 2][r] = av.z; As[c + 3][r] = av.w;
    int r2 = tid >> 4, c2 = (tid & 15) * 4;
    float4 bv = *(const float4*)(W + (size_t)(k0 + r2) * Nn + col0 + c2);
    *(float4*)(&Bs[r2][c2]) = bv;
    __syncthreads();
#pragma unroll
    for (int kk = 0; kk < 16; ++kk) {
      float4 a4 = *(const float4*)(&As[kk][ty * 4]);
      float4 b4 = *(const float4*)(&Bs[kk][tx * 4]);
      float a[4] = {a4.x, a4.y, a4.z, a4.w};
      float b[4] = {b4.x, b4.y, b4.z, b4.w};
#pragma unroll
      for (int i = 0; i < 4; ++i)
#pragma unroll
        for (int j = 0; j < 4; ++j)
          acc[i][j] += a[i] * b[j];
    }
    __syncthreads();
  }
#pragma unroll
  for (int i = 0; i < 4; ++i) {
    int row = row0 + ty * 4 + i;
#pragma unroll
    for (int j = 0; j < 4; ++j) {
      int col = col0 + tx * 4 + j;
      C[(size_t)row * Nn + col] = acc[i][j] + bias[col];
    }
  }
}

// ---------------- DPP helper: rotate-add within row16 ----------------
template <int N>
__device__ __forceinline__ float ror_add(float x) {
  int xi = __float_as_int(x);
  int yi = __builtin_amdgcn_update_dpp(xi, xi, 0x100 + N, 0xF, 0xF, false);
  return x + __int_as_float(yi);
}

__device__ __forceinline__ float sigm(float x) { return 1.f / (1.f + __expf(-x)); }

// ---------------- K3: LSTM, 256 WGs (128/dir, 4 units each), fence-free ----------------
// All cross-WG h traffic via RELAXED agent-scope atomics (MALL, no cache maintenance).
// Ordering: data stores -> s_waitcnt vmcnt(0) -> flag add. Spin on relaxed flag load.
__global__ __launch_bounds__(512, 1) void k_lstm4(
    const float* __restrict__ Whf, const float* __restrict__ Whb,
    const float* __restrict__ GXfp, const float* __restrict__ GXbp,
    const float* __restrict__ maskp, float* __restrict__ Hbuf,
    float* __restrict__ ctx, int* __restrict__ flags) {
  extern __shared__ float lds[];
  float* Whs  = lds;                    // [16 gate-cols][512]
  float* Hs   = lds + 8192;             // [32 b][516]
  float* part = lds + 8192 + 16512;     // [2][16 gc][36]
  const int tid = threadIdx.x;
  const int wg  = blockIdx.x;
  const int dir = wg & 1;
  const int grp = wg >> 1;              // 0..127
  const int j0  = grp * 4;              // 4 hidden units per WG
  const float* Wh = dir ? Whb : Whf;
  const float* GX = dir ? GXbp : GXfp;
  int* cnt = flags + dir * 64;          // 256B apart

  // ---- stage Wh slice: Whs[c][k], c = q*4+u  (gcol = q*HH + j0 + u) ----
  for (int i = tid; i < 16 * 512; i += 512) {
    int c = i >> 9, k = i & 511;
    int q = c >> 2, u = c & 3;
    Whs[c * 512 + k] = Wh[(size_t)k * G4 + q * HH + j0 + u];
  }
  // ---- zero my h slice (parity 0) via relaxed agent stores ----
  if (tid < 128) {
    int u = tid & 3, b = tid >> 2;
    __hip_atomic_store(&Hbuf[(size_t)(0 * 2 + dir) * 16384 + b * HH + j0 + u], 0.f,
                       __ATOMIC_RELAXED, __HIP_MEMORY_SCOPE_AGENT);
  }
  asm volatile("s_waitcnt vmcnt(0)" ::: "memory");
  __syncthreads();
  if (tid == 0)
    __hip_atomic_fetch_add(cnt, 1, __ATOMIC_RELAXED, __HIP_MEMORY_SCOPE_AGENT);

  const int ks = tid & 31;              // k-slice lane (16 k-vals, stride-4)
  const int cq = (tid >> 5) & 3;        // col quarter (4 cols)
  const int bq = tid >> 7;              // batch quarter (8 batches)
  const int uu = tid & 3, bb = tid >> 2; // combine map (tid<128)
  float cstate = 0.f;
  int par = 0;

  for (int s = 0; s < LL; ++s) {
    const int t = dir ? (LL - 1 - s) : s;

    // ---- prefetch GX + mask (plain cached loads, independent of h) ----
    float gx0 = 0.f, gx1 = 0.f, gx2 = 0.f, gx3 = 0.f, mval = 0.f;
    if (tid < 128) {
      const float* gp = GX + ((size_t)(bb * LL + t)) * G4 + j0 + uu;
      gx0 = gp[0]; gx1 = gp[512]; gx2 = gp[1024]; gx3 = gp[1536];
      mval = maskp[bb * LL + t];
    }

    // ---- wait for all WGs of my dir to finish step s-1 ----
    if (tid == 0) {
      int target = 128 * (s + 1);
      int it = 0;
      while (__hip_atomic_load(cnt, __ATOMIC_RELAXED, __HIP_MEMORY_SCOPE_AGENT) < target) {
        __builtin_amdgcn_s_sleep(2);
        if (++it > (1 << 18)) break;   // hang guard
      }
    }
    __syncthreads();
    __builtin_amdgcn_sched_barrier(0);

    // ---- load h[par] (64KB) via relaxed agent 8B loads; stage to LDS ----
    {
      const unsigned long long* hb64 =
          (const unsigned long long*)(Hbuf + (size_t)(par * 2 + dir) * 16384);
      unsigned long long hv[16];
#pragma unroll
      for (int m = 0; m < 16; ++m)
        hv[m] = __hip_atomic_load(&hb64[tid + 512 * m], __ATOMIC_RELAXED,
                                  __HIP_MEMORY_SCOPE_AGENT);
#pragma unroll
      for (int m = 0; m < 16; ++m) {
        int f = 2 * (tid + 512 * m);
        int b = f >> 9, k = f & 511;
        *(float2*)(&Hs[b * 516 + k]) = *(float2*)(&hv[m]);
      }
    }
    __syncthreads();

    // ---- 4x8 register-tiled matvec, lane-strided k (conflict-free b128) ----
    float acc[4][8];
#pragma unroll
    for (int ci = 0; ci < 4; ++ci)
#pragma unroll
      for (int bi = 0; bi < 8; ++bi) acc[ci][bi] = 0.f;
    {
      const float* wp = Whs + (cq * 4) * 512 + 4 * ks;
      const float* hp = Hs + (bq * 8) * 516 + 4 * ks;
#pragma unroll
      for (int j = 0; j < 4; ++j) {
        const int ko = 128 * j;
        float4 w4[4], h4[8];
#pragma unroll
        for (int ci = 0; ci < 4; ++ci) w4[ci] = *(const float4*)(wp + ci * 512 + ko);
#pragma unroll
        for (int bi = 0; bi < 8; ++bi) h4[bi] = *(const float4*)(hp + bi * 516 + ko);
#pragma unroll
        for (int ci = 0; ci < 4; ++ci) {
          float4 w = w4[ci];
#pragma unroll
          for (int bi = 0; bi < 8; ++bi) {
            float4 h = h4[bi];
            acc[ci][bi] += w.x * h.x + w.y * h.y + w.z * h.z + w.w * h.w;
          }
        }
      }
    }
    // ---- reduce over ks within row16 (ror-allreduce), 2 partials ----
#pragma unroll
    for (int ci = 0; ci < 4; ++ci)
#pragma unroll
      for (int bi = 0; bi < 8; ++bi) {
        float v = acc[ci][bi];
        v = ror_add<1>(v); v = ror_add<2>(v); v = ror_add<4>(v); v = ror_add<8>(v);
        acc[ci][bi] = v;
      }
    if ((ks & 15) == 0) {
      const int ph = ks >> 4;
      float* dst = part + ph * 576 + (cq * 4) * 36 + bq * 8;
#pragma unroll
      for (int ci = 0; ci < 4; ++ci) {
        *(float4*)(dst + ci * 36 + 0) = make_float4(acc[ci][0], acc[ci][1], acc[ci][2], acc[ci][3]);
        *(float4*)(dst + ci * 36 + 4) = make_float4(acc[ci][4], acc[ci][5], acc[ci][6], acc[ci][7]);
      }
    }
    __syncthreads();

    // ---- gate combine (tid<128): unit uu, batch bb ----
    if (tid < 128) {
      float pre[4];
#pragma unroll
      for (int q = 0; q < 4; ++q) {
        int c = q * 4 + uu;
        pre[q] = part[c * 36 + bb] + part[576 + c * 36 + bb];
      }
      pre[0] += gx0; pre[1] += gx1; pre[2] += gx2; pre[3] += gx3;
      float gi = sigm(pre[0]);
      float gf = sigm(pre[1]);
      float gg = tanhf(pre[2]);
      float go = sigm(pre[3]);
      float cnew = gf * cstate + gi * gg;
      float hnew = go * tanhf(cnew);
      float hold = Hs[bb * 516 + j0 + uu];
      float hn = hnew * mval + hold * (1.f - mval);
      cstate = cnew * mval + cstate * (1.f - mval);
      __hip_atomic_store(&Hbuf[(size_t)((par ^ 1) * 2 + dir) * 16384 + bb * HH + j0 + uu],
                         hn, __ATOMIC_RELAXED, __HIP_MEMORY_SCOPE_AGENT);
      ctx[((size_t)(bb * LL + t)) * (2 * HH) + dir * HH + j0 + uu] = hn;
    }
    asm volatile("s_waitcnt vmcnt(0)" ::: "memory");
    __syncthreads();
    if (tid == 0)
      __hip_atomic_fetch_add(cnt, 1, __ATOMIC_RELAXED, __HIP_MEMORY_SCOPE_AGENT);
    par ^= 1;
  }
}

__global__ void k_init0(int* __restrict__ flags) { flags[threadIdx.x] = 0; }

// ---------------- K4: tag histogram + stable compaction ----------------
__global__ void k_zero16(int* counts) { if (threadIdx.x < 16) counts[threadIdx.x] = 0; }

__global__ void k_count(const int* __restrict__ posi, int* __restrict__ counts) {
  int t = blockIdx.x * 256 + threadIdx.x;
  if (t < TT) atomicAdd(&counts[posi[t]], 1);
}

__global__ void k_prefix(const int* __restrict__ counts, int* __restrict__ offs) {
  if (threadIdx.x == 0) {
    int a = 0;
    for (int p = 0; p < NTAGS; ++p) { offs[p] = a; a += counts[p]; }
    offs[NTAGS] = a;
  }
}

__global__ __launch_bounds__(256) void k_compact(const int* __restrict__ posi,
    const int* __restrict__ offs, int* __restrict__ idxlist) {
  int p = blockIdx.x, tid = threadIdx.x;
  __shared__ int sc[256];
  __shared__ int sbase;
  if (tid == 0) sbase = offs[p];
  __syncthreads();
  for (int c0 = 0; c0 < TT; c0 += 256) {
    int t = c0 + tid;
    int f = (posi[t] == p) ? 1 : 0;
    int v = f;
    sc[tid] = v;
    __syncthreads();
    for (int o = 1; o < 256; o <<= 1) {
      int add = (tid >= o) ? sc[tid - o] : 0;
      __syncthreads();
      v += add;
      sc[tid] = v;
      __syncthreads();
    }
    int total = sc[255];
    int base = sbase;
    if (f) idxlist[base + v - 1] = t;
    __syncthreads();
    if (tid == 0) sbase = base + total;
    __syncthreads();
  }
}

// ---------------- K4b: gather per-tag psr rows ----------------
__global__ void k_ptbl(const int* __restrict__ wtbl, const float* __restrict__ psrw,
                       float* __restrict__ Ptbl) {
  int i = blockIdx.x * 256 + threadIdx.x;
  int total = NTAGS * MM * EE;
  for (; i < total; i += gridDim.x * 256) {
    int p = i / (MM * EE);
    int rem = i - p * (MM * EE);
    int r = rem / EE;
    int e = rem - r * EE;
    Ptbl[i] = psrw[(size_t)wtbl[p * MM + r] * EE + e];
  }
}

// ---------------- K5: grouped decoder GEMM ----------------
__global__ __launch_bounds__(256) void k_decgemm(const float* __restrict__ ctxb,
    const float* __restrict__ decW, const float* __restrict__ decb,
    const int* __restrict__ counts, const int* __restrict__ offs,
    const int* __restrict__ idxlist, float* __restrict__ Z) {
  int p = blockIdx.z;
  int n = counts[p];
  int r0 = blockIdx.y * 64;
  if (r0 >= n) return;
  int col0 = blockIdx.x * 64;
  __shared__ float As[16][68];
  __shared__ float Bs[16][64];
  __shared__ int rows[64];
  int tid = threadIdx.x;
  if (tid < 64) {
    int r = r0 + tid;
    rows[tid] = idxlist[offs[p] + (r < n ? r : 0)];
  }
  __syncthreads();
  const float* W = decW + (size_t)p * MM * MM;
  float acc[4][4] = {};
  for (int k0 = 0; k0 < MM; k0 += 16) {
    int r = tid >> 2, c = (tid & 3) * 4;
    float4 av = *(const float4*)(ctxb + (size_t)rows[r] * MM + k0 + c);
    As[c + 0][r] = av.x; As[c + 1][r] = av.y; As[c + 2][r] = av.z; As[c + 3][r] = av.w;
    int r2 = tid >> 4, c2 = (tid & 15) * 4;
    float4 bv = *(const float4*)(W + (size_t)(k0 + r2) * MM + col0 + c2);
    *(float4*)(&Bs[r2][c2]) = bv;
    __syncthreads();
#pragma unroll
    for (int kk = 0; kk < 16; ++kk) {
      float4 a4 = *(const float4*)(&As[kk][(tid >> 4) * 4]);
      float4 b4 = *(const float4*)(&Bs[kk][(tid & 15) * 4]);
      float a[4] = {a4.x, a4.y, a4.z, a4.w};
      float b[4] = {b4.x, b4.y, b4.z, b4.w};
#pragma unroll
      for (int i = 0; i < 4; ++i)
#pragma unroll
        for (int j = 0; j < 4; ++j)
          acc[i][j] += a[i] * b[j];
    }
    __syncthreads();
  }
  int tx = tid & 15, ty = tid >> 4;
#pragma unroll
  for (int i = 0; i < 4; ++i) {
    int r = r0 + ty * 4 + i;
    if (r < n) {
      int tok = rows[ty * 4 + i];
#pragma unroll
      for (int j = 0; j < 4; ++j) {
        int col = col0 + tx * 4 + j;
        Z[(size_t)tok * MM + col] = acc[i][j] + decb[p * MM + col];
      }
    }
  }
}

// ---------------- K6: per-token softmax / entropy / gumbel argmax ----------------
__global__ __launch_bounds__(256) void k_softmax(
    const float* __restrict__ Z, const float* __restrict__ gum,
    const int* __restrict__ posi, const int* __restrict__ wflat,
    const int* __restrict__ wtbl, float* __restrict__ SPT,
    float* __restrict__ rowent, int* __restrict__ avoidb,
    float* __restrict__ out_word, float* __restrict__ out_mask,
    float* __restrict__ out_pri) {
  __shared__ float red[256];
  __shared__ float redv[256];
  __shared__ int redi[256];
  int t = blockIdx.x, tid = threadIdx.x;
  float z[4];
#pragma unroll
  for (int i = 0; i < 4; ++i) z[i] = Z[(size_t)t * MM + tid + 256 * i];
  float mx = fmaxf(fmaxf(z[0], z[1]), fmaxf(z[2], z[3]));
  red[tid] = mx; __syncthreads();
  for (int o = 128; o > 0; o >>= 1) { if (tid < o) red[tid] = fmaxf(red[tid], red[tid + o]); __syncthreads(); }
  mx = red[0]; __syncthreads();
  float se = 0.f;
#pragma unroll
  for (int i = 0; i < 4; ++i) se += expf(z[i] - mx);
  red[tid] = se; __syncthreads();
  for (int o = 128; o > 0; o >>= 1) { if (tid < o) red[tid] += red[tid + o]; __syncthreads(); }
  float lse = logf(red[0]); __syncthreads();
  float lp[4]; float ent = 0.f;
#pragma unroll
  for (int i = 0; i < 4; ++i) { lp[i] = z[i] - mx - lse; ent -= lp[i] * expf(lp[i]); }
  red[tid] = ent; __syncthreads();
  for (int o = 128; o > 0; o >>= 1) { if (tid < o) red[tid] += red[tid + o]; __syncthreads(); }
  float enttot = red[0]; __syncthreads();
  float y[4];
#pragma unroll
  for (int i = 0; i < 4; ++i) {
    float u = gum[(size_t)t * MM + tid + 256 * i];
    float g = -logf(-logf(u + 1e-10f) + 1e-10f);
    y[i] = lp[i] + g;
  }
  float bv = y[0]; int bi = tid;
#pragma unroll
  for (int i = 1; i < 4; ++i) { int j = tid + 256 * i; if (y[i] > bv) { bv = y[i]; bi = j; } }
  redv[tid] = bv; redi[tid] = bi; __syncthreads();
  for (int o = 128; o > 0; o >>= 1) {
    if (tid < o) {
      float v2 = redv[tid + o]; int i2 = redi[tid + o];
      if (v2 > redv[tid] || (v2 == redv[tid] && i2 < redi[tid])) { redv[tid] = v2; redi[tid] = i2; }
    }
    __syncthreads();
  }
  float ymax = redv[0]; int amax = redi[0]; __syncthreads();
  float e[4]; float s2 = 0.f;
#pragma unroll
  for (int i = 0; i < 4; ++i) { e[i] = expf(y[i] - ymax); s2 += e[i]; }
  red[tid] = s2; __syncthreads();
  for (int o = 128; o > 0; o >>= 1) { if (tid < o) red[tid] += red[tid + o]; __syncthreads(); }
  float inv = 1.f / red[0];
#pragma unroll
  for (int i = 0; i < 4; ++i) SPT[(size_t)t * MM + tid + 256 * i] = e[i] * inv;
  if (tid == 0) {
    int p = posi[t];
    int widx = wtbl[p * MM + amax];
    int wf = wflat[t];
    int avoid = (widx == wf) ? 1 : 0;
    avoidb[t] = avoid;
    out_word[t] = (float)(avoid ? 0 : widx);
    out_mask[t] = 1.0f;
    out_pri[t] = (p < 4) ? 1.0f : 0.0f;
    rowent[t] = enttot;
  }
}

// ---------------- K7: grouped emb GEMM ----------------
__global__ __launch_bounds__(256) void k_embgemm(const float* __restrict__ SPT,
    const float* __restrict__ Ptbl, const float* __restrict__ psrw,
    const int* __restrict__ counts, const int* __restrict__ offs,
    const int* __restrict__ idxlist, const int* __restrict__ avoidb,
    float* __restrict__ out_emb) {
  int p = blockIdx.y;
  int n = counts[p];
  int r0 = blockIdx.x * 64;
  if (r0 >= n) return;
  __shared__ float As[16][68];
  __shared__ float Bs[16][132];
  __shared__ int rows[64];
  int tid = threadIdx.x;
  if (tid < 64) rows[tid] = idxlist[offs[p] + ((r0 + tid) < n ? (r0 + tid) : 0)];
  __syncthreads();
  const float* P = Ptbl + (size_t)p * MM * EE;
  int tx = tid & 31, ty = tid >> 5;
  float acc[8][4] = {};
  for (int k0 = 0; k0 < MM; k0 += 16) {
    int r = tid >> 2, c = (tid & 3) * 4;
    float4 av = *(const float4*)(SPT + (size_t)rows[r] * MM + k0 + c);
    As[c + 0][r] = av.x; As[c + 1][r] = av.y; As[c + 2][r] = av.z; As[c + 3][r] = av.w;
    int r2 = tid >> 4;
    int c2 = (tid & 15) * 8;
    float4 b0 = make_float4(0.f, 0.f, 0.f, 0.f), b1 = make_float4(0.f, 0.f, 0.f, 0.f);
    if (c2 + 3 < EE) b0 = *(const float4*)(P + (size_t)(k0 + r2) * EE + c2);
    if (c2 + 7 < EE) b1 = *(const float4*)(P + (size_t)(k0 + r2) * EE + c2 + 4);
    *(float4*)(&Bs[r2][c2]) = b0;
    *(float4*)(&Bs[r2][c2 + 4]) = b1;
    __syncthreads();
#pragma unroll
    for (int kk = 0; kk < 16; ++kk) {
      float4 b4 = *(const float4*)(&Bs[kk][tx * 4]);
      float4 a0 = *(const float4*)(&As[kk][ty * 8]);
      float4 a1 = *(const float4*)(&As[kk][ty * 8 + 4]);
      float a[8] = {a0.x, a0.y, a0.z, a0.w, a1.x, a1.y, a1.z, a1.w};
#pragma unroll
      for (int ri = 0; ri < 8; ++ri) {
        acc[ri][0] += a[ri] * b4.x; acc[ri][1] += a[ri] * b4.y;
        acc[ri][2] += a[ri] * b4.z; acc[ri][3] += a[ri] * b4.w;
      }
    }
    __syncthreads();
  }
#pragma unroll
  for (int ri = 0; ri < 8; ++ri) {
    int r = ty * 8 + ri;
    if (r0 + r < n) {
      int tok = rows[r];
      int av = avoidb[tok];
#pragma unroll
      for (int j = 0; j < 4; ++j) {
        int col = tx * 4 + j;
        if (col < EE) {
          float v = av ? psrw[col] : acc[ri][j];
          out_emb[(size_t)tok * EE + col] = v;
        }
      }
    }
  }
}

// ---------------- K8: deterministic entropy-loss reduction ----------------
__global__ __launch_bounds__(256) void k_final(const float* __restrict__ rowent,
    const int* __restrict__ posi, const int* __restrict__ counts,
    float* __restrict__ out_loss) {
  __shared__ float red[256];
  int tid = threadIdx.x;
  float s = 0.f;
  for (int t = tid; t < TT; t += 256) {
    int p = posi[t];
    float denom = fmaxf((float)counts[p] * (float)MM, 1.0f);
    s += rowent[t] / denom;
  }
  red[tid] = s; __syncthreads();
  for (int o = 128; o > 0; o >>= 1) { if (tid < o) red[tid] += red[tid + o]; __syncthreads(); }
  if (tid == 0) out_loss[0] = -red[0] * 0.01f;
}

// ---------------- launcher ----------------
extern "C" void kernel_launch(void* const* d_in, const int* in_sizes, int n_in,
                              void* d_out, int out_size, void* d_ws, size_t ws_size,
                              hipStream_t stream) {
  const int*   inp_word = (const int*)d_in[0];
  const int*   inp_pos  = (const int*)d_in[1];
  const float* inp_mask = (const float*)d_in[2];
  const float* gum      = (const float*)d_in[3];
  const float* wemb     = (const float*)d_in[4];
  const float* pemb     = (const float*)d_in[5];
  const float* Wx_f     = (const float*)d_in[6];
  const float* Wh_f     = (const float*)d_in[7];
  const float* b_f      = (const float*)d_in[8];
  const float* Wx_b     = (const float*)d_in[9];
  const float* Wh_b     = (const float*)d_in[10];
  const float* b_b      = (const float*)d_in[11];
  const float* decW     = (const float*)d_in[12];
  const float* decb     = (const float*)d_in[13];
  const int*   wtbl     = (const int*)d_in[14];
  const float* psrw     = (const float*)d_in[15];

  float* out_word = (float*)d_out;
  float* out_emb  = out_word + TT;
  float* out_mask = out_emb + (size_t)TT * EE;
  float* out_pri  = out_mask + TT;
  float* out_loss = out_pri + TT;

  float* ws = (float*)d_ws;
  float* X      = ws;
  float* GXf    = X + (size_t)TT * DIN;
  float* GXb    = GXf + (size_t)TT * G4;
  float* ctxb   = GXb + (size_t)TT * G4;
  float* Hbuf   = ctxb + (size_t)TT * MM;
  float* rowent = Hbuf + 2 * 2 * BB * HH;
  int* avoidb   = (int*)(rowent + TT);
  int* counts   = avoidb + TT;
  int* offs     = counts + 16;
  int* idxlist  = offs + 32;
  int* flags    = idxlist + TT;
  float* Z    = GXf;   // reuse: GX dead after LSTM
  float* SPT  = Z;     // in-place row rewrite in k_softmax
  float* Ptbl = GXb;   // reuse

  k_embed<<<TT, 64, 0, stream>>>(inp_word, inp_pos, wemb, pemb, X);
  k_gemm_bias<<<dim3(G4 / 64, TT / 64), 256, 0, stream>>>(X, Wx_f, b_f, GXf, TT, G4, DIN);
  k_gemm_bias<<<dim3(G4 / 64, TT / 64), 256, 0, stream>>>(X, Wx_b, b_b, GXb, TT, G4, DIN);

  k_init0<<<1, 128, 0, stream>>>(flags);
  {
    const int ldsz = (8192 + 16512 + 1152) * 4;  // 103424 B
    hipFuncSetAttribute((const void*)k_lstm4,
                        hipFuncAttributeMaxDynamicSharedMemorySize, ldsz);
    k_lstm4<<<256, 512, ldsz, stream>>>(Wh_f, Wh_b, GXf, GXb, inp_mask, Hbuf, ctxb, flags);
  }

  k_zero16<<<1, 64, 0, stream>>>(counts);
  k_count<<<TT / 256, 256, 0, stream>>>(inp_pos, counts);
  k_prefix<<<1, 64, 0, stream>>>(counts, offs);
  k_compact<<<NTAGS, 256, 0, stream>>>(inp_pos, offs, idxlist);
  k_ptbl<<<1024, 256, 0, stream>>>(wtbl, psrw, Ptbl);
  k_decgemm<<<dim3(MM / 64, TT / 64, NTAGS), 256, 0, stream>>>(ctxb, decW, decb, counts, offs, idxlist, Z);
  k_softmax<<<TT, 256, 0, stream>>>(Z, gum, inp_pos, inp_word, wtbl, SPT, rowent, avoidb,
                                    out_word, out_mask, out_pri);
  k_embgemm<<<dim3(TT / 64, NTAGS), 256, 0, stream>>>(SPT, Ptbl, psrw, counts, offs, idxlist,
                                                      avoidb, out_emb);
  k_final<<<1, 256, 0, stream>>>(rowent, inp_pos, counts, out_loss);
}

// Round 5
// 2549.409 us; speedup vs baseline: 10.7359x; 1.0793x over previous
//
#include <hip/hip_runtime.h>
#include <math.h>
#include <cstdint>

#define BB 32
#define LL 256
#define TT 8192     // B*L
#define DIN 256
#define WEDm 200
#define PEDm 56
#define HH 512
#define G4 2048
#define MM 1024
#define EE 100
#define NTAGS 16

// ---------------- K1: embedding concat ----------------
__global__ void k_embed(const int* __restrict__ word, const int* __restrict__ posi,
                        const float* __restrict__ wemb, const float* __restrict__ pemb,
                        float* __restrict__ X) {
  int t = blockIdx.x;
  int c = threadIdx.x * 4;
  float4 v;
  if (c < WEDm) {
    int w = word[t];
    v = *(const float4*)(wemb + (size_t)w * WEDm + c);
  } else {
    int p = posi[t];
    v = *(const float4*)(pemb + (size_t)p * PEDm + (c - WEDm));
  }
  *(float4*)(X + (size_t)t * DIN + c) = v;
}

// ---------------- K2: C = A@W + bias (f32 tiled) ----------------
__global__ __launch_bounds__(256) void k_gemm_bias(const float* __restrict__ A,
    const float* __restrict__ W, const float* __restrict__ bias,
    float* __restrict__ C, int Mm, int Nn, int Kk) {
  __shared__ float As[16][68];
  __shared__ float Bs[16][64];
  int tid = threadIdx.x;
  int tx = tid & 15, ty = tid >> 4;
  int row0 = blockIdx.y * 64, col0 = blockIdx.x * 64;
  float acc[4][4] = {};
  for (int k0 = 0; k0 < Kk; k0 += 16) {
    int r = tid >> 2, c = (tid & 3) * 4;
    float4 av = *(const float4*)(A + (size_t)(row0 + r) * Kk + k0 + c);
    As[c + 0][r] = av.x; As[c + 1][r] = av.y; As[c + 2][r] = av.z; As[c + 3][r] = av.w;
    int r2 = tid >> 4, c2 = (tid & 15) * 4;
    float4 bv = *(const float4*)(W + (size_t)(k0 + r2) * Nn + col0 + c2);
    *(float4*)(&Bs[r2][c2]) = bv;
    __syncthreads();
#pragma unroll
    for (int kk = 0; kk < 16; ++kk) {
      float4 a4 = *(const float4*)(&As[kk][ty * 4]);
      float4 b4 = *(const float4*)(&Bs[kk][tx * 4]);
      float a[4] = {a4.x, a4.y, a4.z, a4.w};
      float b[4] = {b4.x, b4.y, b4.z, b4.w};
#pragma unroll
      for (int i = 0; i < 4; ++i)
#pragma unroll
        for (int j = 0; j < 4; ++j)
          acc[i][j] += a[i] * b[j];
    }
    __syncthreads();
  }
#pragma unroll
  for (int i = 0; i < 4; ++i) {
    int row = row0 + ty * 4 + i;
#pragma unroll
    for (int j = 0; j < 4; ++j) {
      int col = col0 + tx * 4 + j;
      C[(size_t)row * Nn + col] = acc[i][j] + bias[col];
    }
  }
}

// ---------------- DPP helper: rotate-add within row16 ----------------
template <int N>
__device__ __forceinline__ float ror_add(float x) {
  int xi = __float_as_int(x);
  int yi = __builtin_amdgcn_update_dpp(xi, xi, 0x100 + N, 0xF, 0xF, false);
  return x + __int_as_float(yi);
}

__device__ __forceinline__ float sigm(float x) { return 1.f / (1.f + __expf(-x)); }

// ---------------- K3: LSTM, 256 WGs (128/dir, 4 units each) ----------------
// Wh register-resident (64 VGPR/thread). Per-WG flag slots (plain relaxed
// agent stores after vmcnt(0) drain) + wide poll (lanes 0..127 spin on
// distinct slots) -- no atomic RMW contention. h via MALL-direct loads.
__global__ __launch_bounds__(512, 1) void k_lstm5(
    const float* __restrict__ Whf, const float* __restrict__ Whb,
    const float* __restrict__ GXfp, const float* __restrict__ GXbp,
    const float* __restrict__ maskp, float* __restrict__ Hbuf,
    float* __restrict__ ctx, int* __restrict__ flags) {
  extern __shared__ float lds[];
  float* Whs  = lds;                // init only: [16 gc][512] (32KB), then dead
  float* Hs   = lds;                // [32 b][516] overlays Whs after reg copy
  float* part = lds + 16512;        // [2][16 gc][36]
  const int tid = threadIdx.x;
  const int wg  = blockIdx.x;
  const int dir = wg & 1;
  const int grp = wg >> 1;          // 0..127
  const int j0  = grp * 4;          // 4 hidden units per WG
  const float* Wh = dir ? Whb : Whf;
  const float* GX = dir ? GXbp : GXfp;

  const int ks = tid & 31;               // k lane: k = 4*ks + 128*j
  const int cq = (tid >> 5) & 3;         // col quarter (4 gate cols)
  const int bq = tid >> 7;               // batch quarter (8 batches)
  const int uu = tid & 3, bb = tid >> 2; // combine map (tid<128)

  // ---- stage Wh slice into LDS, then copy my slice to registers ----
  for (int i = tid; i < 16 * 512; i += 512) {
    int c = i >> 9, k = i & 511;
    Whs[c * 512 + k] = Wh[(size_t)k * G4 + (c >> 2) * HH + j0 + (c & 3)];
  }
  __syncthreads();
  float4 wreg[4][4];
#pragma unroll
  for (int ci = 0; ci < 4; ++ci)
#pragma unroll
    for (int j = 0; j < 4; ++j)
      wreg[ci][j] = *(const float4*)(Whs + (cq * 4 + ci) * 512 + 4 * ks + 128 * j);
  __syncthreads();   // Whs dead; Hs may overlay

  // ---- zero my h slice (parity 0) via relaxed agent stores; publish ----
  if (tid < 128) {
    __hip_atomic_store(&Hbuf[(size_t)(0 * 2 + dir) * 16384 + bb * HH + j0 + uu], 0.f,
                       __ATOMIC_RELAXED, __HIP_MEMORY_SCOPE_AGENT);
  }
  asm volatile("s_waitcnt vmcnt(0)" ::: "memory");
  __syncthreads();
  if (tid == 0)
    __hip_atomic_store(&flags[wg], 1, __ATOMIC_RELAXED, __HIP_MEMORY_SCOPE_AGENT);

  float cstate = 0.f;
  int par = 0;

  for (int s = 0; s < LL; ++s) {
    const int t = dir ? (LL - 1 - s) : s;

    // ---- prefetch GX + mask (plain cached loads, independent of h) ----
    float gx0 = 0.f, gx1 = 0.f, gx2 = 0.f, gx3 = 0.f, mval = 0.f;
    if (tid < 128) {
      const float* gp = GX + ((size_t)(bb * LL + t)) * G4 + j0 + uu;
      gx0 = gp[0]; gx1 = gp[512]; gx2 = gp[1024]; gx3 = gp[1536];
      mval = maskp[bb * LL + t];
    }

    // ---- wide poll: lane g waits for WG (2g+dir) to reach step s ----
    if (tid < 128) {
      int it = 0;
      while (__hip_atomic_load(&flags[2 * tid + dir], __ATOMIC_RELAXED,
                               __HIP_MEMORY_SCOPE_AGENT) < s + 1) {
        __builtin_amdgcn_s_sleep(1);
        if (++it > (1 << 20)) break;   // hang guard
      }
    }
    __syncthreads();
    __builtin_amdgcn_sched_barrier(0);

    // ---- load h[par] (64KB) via relaxed agent 8B loads; stage to LDS ----
    {
      const unsigned long long* hb64 =
          (const unsigned long long*)(Hbuf + (size_t)(par * 2 + dir) * 16384);
      unsigned long long hv[16];
#pragma unroll
      for (int m = 0; m < 16; ++m)
        hv[m] = __hip_atomic_load(&hb64[tid + 512 * m], __ATOMIC_RELAXED,
                                  __HIP_MEMORY_SCOPE_AGENT);
#pragma unroll
      for (int m = 0; m < 16; ++m) {
        int f = 2 * (tid + 512 * m);
        int b = f >> 9, k = f & 511;
        *(float2*)(&Hs[b * 516 + k]) = *(float2*)(&hv[m]);
      }
    }
    __syncthreads();

    // ---- 4x8 register-tiled matvec; Wh from regs, h from LDS ----
    float acc[4][8];
#pragma unroll
    for (int ci = 0; ci < 4; ++ci)
#pragma unroll
      for (int bi = 0; bi < 8; ++bi) acc[ci][bi] = 0.f;
    {
      const float* hp = Hs + (bq * 8) * 516 + 4 * ks;
#pragma unroll
      for (int j = 0; j < 4; ++j) {
        const int ko = 128 * j;
        float4 h4[8];
#pragma unroll
        for (int bi = 0; bi < 8; ++bi) h4[bi] = *(const float4*)(hp + bi * 516 + ko);
#pragma unroll
        for (int ci = 0; ci < 4; ++ci) {
          float4 w = wreg[ci][j];
#pragma unroll
          for (int bi = 0; bi < 8; ++bi) {
            float4 h = h4[bi];
            acc[ci][bi] += w.x * h.x + w.y * h.y + w.z * h.z + w.w * h.w;
          }
        }
      }
    }
    // ---- reduce over ks within row16 (ror-allreduce), 2 partials ----
#pragma unroll
    for (int ci = 0; ci < 4; ++ci)
#pragma unroll
      for (int bi = 0; bi < 8; ++bi) {
        float v = acc[ci][bi];
        v = ror_add<1>(v); v = ror_add<2>(v); v = ror_add<4>(v); v = ror_add<8>(v);
        acc[ci][bi] = v;
      }
    if ((ks & 15) == 0) {
      const int ph = ks >> 4;
      float* dst = part + ph * 576 + (cq * 4) * 36 + bq * 8;
#pragma unroll
      for (int ci = 0; ci < 4; ++ci) {
        *(float4*)(dst + ci * 36 + 0) = make_float4(acc[ci][0], acc[ci][1], acc[ci][2], acc[ci][3]);
        *(float4*)(dst + ci * 36 + 4) = make_float4(acc[ci][4], acc[ci][5], acc[ci][6], acc[ci][7]);
      }
    }
    __syncthreads();

    // ---- gate combine (tid<128): unit uu, batch bb ----
    float hn = 0.f;
    if (tid < 128) {
      float pre[4];
#pragma unroll
      for (int q = 0; q < 4; ++q) {
        int c = q * 4 + uu;
        pre[q] = part[c * 36 + bb] + part[576 + c * 36 + bb];
      }
      pre[0] += gx0; pre[1] += gx1; pre[2] += gx2; pre[3] += gx3;
      float gi = sigm(pre[0]);
      float gf = sigm(pre[1]);
      float gg = tanhf(pre[2]);
      float go = sigm(pre[3]);
      float cnew = gf * cstate + gi * gg;
      float hnew = go * tanhf(cnew);
      float hold = Hs[bb * 516 + j0 + uu];
      hn = hnew * mval + hold * (1.f - mval);
      cstate = cnew * mval + cstate * (1.f - mval);
      __hip_atomic_store(&Hbuf[(size_t)((par ^ 1) * 2 + dir) * 16384 + bb * HH + j0 + uu],
                         hn, __ATOMIC_RELAXED, __HIP_MEMORY_SCOPE_AGENT);
    }
    asm volatile("s_waitcnt vmcnt(0)" ::: "memory");
    __syncthreads();
    if (tid == 0)
      __hip_atomic_store(&flags[wg], s + 2, __ATOMIC_RELAXED, __HIP_MEMORY_SCOPE_AGENT);
    // ctx store off the critical publish path
    if (tid < 128)
      ctx[((size_t)(bb * LL + t)) * (2 * HH) + dir * HH + j0 + uu] = hn;
    par ^= 1;
  }
}

__global__ void k_init0(int* __restrict__ flags) { flags[threadIdx.x] = 0; }

// ---------------- K4: tag histogram + stable compaction ----------------
__global__ void k_zero16(int* counts) { if (threadIdx.x < 16) counts[threadIdx.x] = 0; }

__global__ void k_count(const int* __restrict__ posi, int* __restrict__ counts) {
  int t = blockIdx.x * 256 + threadIdx.x;
  if (t < TT) atomicAdd(&counts[posi[t]], 1);
}

__global__ void k_prefix(const int* __restrict__ counts, int* __restrict__ offs) {
  if (threadIdx.x == 0) {
    int a = 0;
    for (int p = 0; p < NTAGS; ++p) { offs[p] = a; a += counts[p]; }
    offs[NTAGS] = a;
  }
}

__global__ __launch_bounds__(256) void k_compact(const int* __restrict__ posi,
    const int* __restrict__ offs, int* __restrict__ idxlist) {
  int p = blockIdx.x, tid = threadIdx.x;
  __shared__ int sc[256];
  __shared__ int sbase;
  if (tid == 0) sbase = offs[p];
  __syncthreads();
  for (int c0 = 0; c0 < TT; c0 += 256) {
    int t = c0 + tid;
    int f = (posi[t] == p) ? 1 : 0;
    int v = f;
    sc[tid] = v;
    __syncthreads();
    for (int o = 1; o < 256; o <<= 1) {
      int add = (tid >= o) ? sc[tid - o] : 0;
      __syncthreads();
      v += add;
      sc[tid] = v;
      __syncthreads();
    }
    int total = sc[255];
    int base = sbase;
    if (f) idxlist[base + v - 1] = t;
    __syncthreads();
    if (tid == 0) sbase = base + total;
    __syncthreads();
  }
}

// ---------------- K4b: gather per-tag psr rows ----------------
__global__ void k_ptbl(const int* __restrict__ wtbl, const float* __restrict__ psrw,
                       float* __restrict__ Ptbl) {
  int i = blockIdx.x * 256 + threadIdx.x;
  int total = NTAGS * MM * EE;
  for (; i < total; i += gridDim.x * 256) {
    int p = i / (MM * EE);
    int rem = i - p * (MM * EE);
    int r = rem / EE;
    int e = rem - r * EE;
    Ptbl[i] = psrw[(size_t)wtbl[p * MM + r] * EE + e];
  }
}

// ---------------- K5: grouped decoder GEMM ----------------
__global__ __launch_bounds__(256) void k_decgemm(const float* __restrict__ ctxb,
    const float* __restrict__ decW, const float* __restrict__ decb,
    const int* __restrict__ counts, const int* __restrict__ offs,
    const int* __restrict__ idxlist, float* __restrict__ Z) {
  int p = blockIdx.z;
  int n = counts[p];
  int r0 = blockIdx.y * 64;
  if (r0 >= n) return;
  int col0 = blockIdx.x * 64;
  __shared__ float As[16][68];
  __shared__ float Bs[16][64];
  __shared__ int rows[64];
  int tid = threadIdx.x;
  if (tid < 64) {
    int r = r0 + tid;
    rows[tid] = idxlist[offs[p] + (r < n ? r : 0)];
  }
  __syncthreads();
  const float* W = decW + (size_t)p * MM * MM;
  float acc[4][4] = {};
  for (int k0 = 0; k0 < MM; k0 += 16) {
    int r = tid >> 2, c = (tid & 3) * 4;
    float4 av = *(const float4*)(ctxb + (size_t)rows[r] * MM + k0 + c);
    As[c + 0][r] = av.x; As[c + 1][r] = av.y; As[c + 2][r] = av.z; As[c + 3][r] = av.w;
    int r2 = tid >> 4, c2 = (tid & 15) * 4;
    float4 bv = *(const float4*)(W + (size_t)(k0 + r2) * MM + col0 + c2);
    *(float4*)(&Bs[r2][c2]) = bv;
    __syncthreads();
#pragma unroll
    for (int kk = 0; kk < 16; ++kk) {
      float4 a4 = *(const float4*)(&As[kk][(tid >> 4) * 4]);
      float4 b4 = *(const float4*)(&Bs[kk][(tid & 15) * 4]);
      float a[4] = {a4.x, a4.y, a4.z, a4.w};
      float b[4] = {b4.x, b4.y, b4.z, b4.w};
#pragma unroll
      for (int i = 0; i < 4; ++i)
#pragma unroll
        for (int j = 0; j < 4; ++j)
          acc[i][j] += a[i] * b[j];
    }
    __syncthreads();
  }
  int tx = tid & 15, ty = tid >> 4;
#pragma unroll
  for (int i = 0; i < 4; ++i) {
    int r = r0 + ty * 4 + i;
    if (r < n) {
      int tok = rows[ty * 4 + i];
#pragma unroll
      for (int j = 0; j < 4; ++j) {
        int col = col0 + tx * 4 + j;
        Z[(size_t)tok * MM + col] = acc[i][j] + decb[p * MM + col];
      }
    }
  }
}

// ---------------- K6: per-token softmax / entropy / gumbel argmax ----------------
__global__ __launch_bounds__(256) void k_softmax(
    const float* __restrict__ Z, const float* __restrict__ gum,
    const int* __restrict__ posi, const int* __restrict__ wflat,
    const int* __restrict__ wtbl, float* __restrict__ SPT,
    float* __restrict__ rowent, int* __restrict__ avoidb,
    float* __restrict__ out_word, float* __restrict__ out_mask,
    float* __restrict__ out_pri) {
  __shared__ float red[256];
  __shared__ float redv[256];
  __shared__ int redi[256];
  int t = blockIdx.x, tid = threadIdx.x;
  float z[4];
#pragma unroll
  for (int i = 0; i < 4; ++i) z[i] = Z[(size_t)t * MM + tid + 256 * i];
  float mx = fmaxf(fmaxf(z[0], z[1]), fmaxf(z[2], z[3]));
  red[tid] = mx; __syncthreads();
  for (int o = 128; o > 0; o >>= 1) { if (tid < o) red[tid] = fmaxf(red[tid], red[tid + o]); __syncthreads(); }
  mx = red[0]; __syncthreads();
  float se = 0.f;
#pragma unroll
  for (int i = 0; i < 4; ++i) se += expf(z[i] - mx);
  red[tid] = se; __syncthreads();
  for (int o = 128; o > 0; o >>= 1) { if (tid < o) red[tid] += red[tid + o]; __syncthreads(); }
  float lse = logf(red[0]); __syncthreads();
  float lp[4]; float ent = 0.f;
#pragma unroll
  for (int i = 0; i < 4; ++i) { lp[i] = z[i] - mx - lse; ent -= lp[i] * expf(lp[i]); }
  red[tid] = ent; __syncthreads();
  for (int o = 128; o > 0; o >>= 1) { if (tid < o) red[tid] += red[tid + o]; __syncthreads(); }
  float enttot = red[0]; __syncthreads();
  float y[4];
#pragma unroll
  for (int i = 0; i < 4; ++i) {
    float u = gum[(size_t)t * MM + tid + 256 * i];
    float g = -logf(-logf(u + 1e-10f) + 1e-10f);
    y[i] = lp[i] + g;
  }
  float bv = y[0]; int bi = tid;
#pragma unroll
  for (int i = 1; i < 4; ++i) { int j = tid + 256 * i; if (y[i] > bv) { bv = y[i]; bi = j; } }
  redv[tid] = bv; redi[tid] = bi; __syncthreads();
  for (int o = 128; o > 0; o >>= 1) {
    if (tid < o) {
      float v2 = redv[tid + o]; int i2 = redi[tid + o];
      if (v2 > redv[tid] || (v2 == redv[tid] && i2 < redi[tid])) { redv[tid] = v2; redi[tid] = i2; }
    }
    __syncthreads();
  }
  float ymax = redv[0]; int amax = redi[0]; __syncthreads();
  float e[4]; float s2 = 0.f;
#pragma unroll
  for (int i = 0; i < 4; ++i) { e[i] = expf(y[i] - ymax); s2 += e[i]; }
  red[tid] = s2; __syncthreads();
  for (int o = 128; o > 0; o >>= 1) { if (tid < o) red[tid] += red[tid + o]; __syncthreads(); }
  float inv = 1.f / red[0];
#pragma unroll
  for (int i = 0; i < 4; ++i) SPT[(size_t)t * MM + tid + 256 * i] = e[i] * inv;
  if (tid == 0) {
    int p = posi[t];
    int widx = wtbl[p * MM + amax];
    int wf = wflat[t];
    int avoid = (widx == wf) ? 1 : 0;
    avoidb[t] = avoid;
    out_word[t] = (float)(avoid ? 0 : widx);
    out_mask[t] = 1.0f;
    out_pri[t] = (p < 4) ? 1.0f : 0.0f;
    rowent[t] = enttot;
  }
}

// ---------------- K7: grouped emb GEMM ----------------
__global__ __launch_bounds__(256) void k_embgemm(const float* __restrict__ SPT,
    const float* __restrict__ Ptbl, const float* __restrict__ psrw,
    const int* __restrict__ counts, const int* __restrict__ offs,
    const int* __restrict__ idxlist, const int* __restrict__ avoidb,
    float* __restrict__ out_emb) {
  int p = blockIdx.y;
  int n = counts[p];
  int r0 = blockIdx.x * 64;
  if (r0 >= n) return;
  __shared__ float As[16][68];
  __shared__ float Bs[16][132];
  __shared__ int rows[64];
  int tid = threadIdx.x;
  if (tid < 64) rows[tid] = idxlist[offs[p] + ((r0 + tid) < n ? (r0 + tid) : 0)];
  __syncthreads();
  const float* P = Ptbl + (size_t)p * MM * EE;
  int tx = tid & 31, ty = tid >> 5;
  float acc[8][4] = {};
  for (int k0 = 0; k0 < MM; k0 += 16) {
    int r = tid >> 2, c = (tid & 3) * 4;
    float4 av = *(const float4*)(SPT + (size_t)rows[r] * MM + k0 + c);
    As[c + 0][r] = av.x; As[c + 1][r] = av.y; As[c + 2][r] = av.z; As[c + 3][r] = av.w;
    int r2 = tid >> 4;
    int c2 = (tid & 15) * 8;
    float4 b0 = make_float4(0.f, 0.f, 0.f, 0.f), b1 = make_float4(0.f, 0.f, 0.f, 0.f);
    if (c2 + 3 < EE) b0 = *(const float4*)(P + (size_t)(k0 + r2) * EE + c2);
    if (c2 + 7 < EE) b1 = *(const float4*)(P + (size_t)(k0 + r2) * EE + c2 + 4);
    *(float4*)(&Bs[r2][c2]) = b0;
    *(float4*)(&Bs[r2][c2 + 4]) = b1;
    __syncthreads();
#pragma unroll
    for (int kk = 0; kk < 16; ++kk) {
      float4 b4 = *(const float4*)(&Bs[kk][tx * 4]);
      float4 a0 = *(const float4*)(&As[kk][ty * 8]);
      float4 a1 = *(const float4*)(&As[kk][ty * 8 + 4]);
      float a[8] = {a0.x, a0.y, a0.z, a0.w, a1.x, a1.y, a1.z, a1.w};
#pragma unroll
      for (int ri = 0; ri < 8; ++ri) {
        acc[ri][0] += a[ri] * b4.x; acc[ri][1] += a[ri] * b4.y;
        acc[ri][2] += a[ri] * b4.z; acc[ri][3] += a[ri] * b4.w;
      }
    }
    __syncthreads();
  }
#pragma unroll
  for (int ri = 0; ri < 8; ++ri) {
    int r = ty * 8 + ri;
    if (r0 + r < n) {
      int tok = rows[r];
      int av = avoidb[tok];
#pragma unroll
      for (int j = 0; j < 4; ++j) {
        int col = tx * 4 + j;
        if (col < EE) {
          float v = av ? psrw[col] : acc[ri][j];
          out_emb[(size_t)tok * EE + col] = v;
        }
      }
    }
  }
}

// ---------------- K8: deterministic entropy-loss reduction ----------------
__global__ __launch_bounds__(256) void k_final(const float* __restrict__ rowent,
    const int* __restrict__ posi, const int* __restrict__ counts,
    float* __restrict__ out_loss) {
  __shared__ float red[256];
  int tid = threadIdx.x;
  float s = 0.f;
  for (int t = tid; t < TT; t += 256) {
    int p = posi[t];
    float denom = fmaxf((float)counts[p] * (float)MM, 1.0f);
    s += rowent[t] / denom;
  }
  red[tid] = s; __syncthreads();
  for (int o = 128; o > 0; o >>= 1) { if (tid < o) red[tid] += red[tid + o]; __syncthreads(); }
  if (tid == 0) out_loss[0] = -red[0] * 0.01f;
}

// ---------------- launcher ----------------
extern "C" void kernel_launch(void* const* d_in, const int* in_sizes, int n_in,
                              void* d_out, int out_size, void* d_ws, size_t ws_size,
                              hipStream_t stream) {
  const int*   inp_word = (const int*)d_in[0];
  const int*   inp_pos  = (const int*)d_in[1];
  const float* inp_mask = (const float*)d_in[2];
  const float* gum      = (const float*)d_in[3];
  const float* wemb     = (const float*)d_in[4];
  const float* pemb     = (const float*)d_in[5];
  const float* Wx_f     = (const float*)d_in[6];
  const float* Wh_f     = (const float*)d_in[7];
  const float* b_f      = (const float*)d_in[8];
  const float* Wx_b     = (const float*)d_in[9];
  const float* Wh_b     = (const float*)d_in[10];
  const float* b_b      = (const float*)d_in[11];
  const float* decW     = (const float*)d_in[12];
  const float* decb     = (const float*)d_in[13];
  const int*   wtbl     = (const int*)d_in[14];
  const float* psrw     = (const float*)d_in[15];

  float* out_word = (float*)d_out;
  float* out_emb  = out_word + TT;
  float* out_mask = out_emb + (size_t)TT * EE;
  float* out_pri  = out_mask + TT;
  float* out_loss = out_pri + TT;

  float* ws = (float*)d_ws;
  float* X      = ws;
  float* GXf    = X + (size_t)TT * DIN;
  float* GXb    = GXf + (size_t)TT * G4;
  float* ctxb   = GXb + (size_t)TT * G4;
  float* Hbuf   = ctxb + (size_t)TT * MM;
  float* rowent = Hbuf + 2 * 2 * BB * HH;
  int* avoidb   = (int*)(rowent + TT);
  int* counts   = avoidb + TT;
  int* offs     = counts + 16;
  int* idxlist  = offs + 32;
  int* flags    = idxlist + TT;
  float* Z    = GXf;   // reuse: GX dead after LSTM
  float* SPT  = Z;     // in-place row rewrite in k_softmax
  float* Ptbl = GXb;   // reuse

  k_embed<<<TT, 64, 0, stream>>>(inp_word, inp_pos, wemb, pemb, X);
  k_gemm_bias<<<dim3(G4 / 64, TT / 64), 256, 0, stream>>>(X, Wx_f, b_f, GXf, TT, G4, DIN);
  k_gemm_bias<<<dim3(G4 / 64, TT / 64), 256, 0, stream>>>(X, Wx_b, b_b, GXb, TT, G4, DIN);

  k_init0<<<1, 256, 0, stream>>>(flags);
  {
    const int ldsz = (16512 + 1152) * 4;  // 70656 B (>= 32KB Whs init region)
    hipFuncSetAttribute((const void*)k_lstm5,
                        hipFuncAttributeMaxDynamicSharedMemorySize, ldsz);
    k_lstm5<<<256, 512, ldsz, stream>>>(Wh_f, Wh_b, GXf, GXb, inp_mask, Hbuf, ctxb, flags);
  }

  k_zero16<<<1, 64, 0, stream>>>(counts);
  k_count<<<TT / 256, 256, 0, stream>>>(inp_pos, counts);
  k_prefix<<<1, 64, 0, stream>>>(counts, offs);
  k_compact<<<NTAGS, 256, 0, stream>>>(inp_pos, offs, idxlist);
  k_ptbl<<<1024, 256, 0, stream>>>(wtbl, psrw, Ptbl);
  k_decgemm<<<dim3(MM / 64, TT / 64, NTAGS), 256, 0, stream>>>(ctxb, decW, decb, counts, offs, idxlist, Z);
  k_softmax<<<TT, 256, 0, stream>>>(Z, gum, inp_pos, inp_word, wtbl, SPT, rowent, avoidb,
                                    out_word, out_mask, out_pri);
  k_embgemm<<<dim3(TT / 64, NTAGS), 256, 0, stream>>>(SPT, Ptbl, psrw, counts, offs, idxlist,
                                                      avoidb, out_emb);
  k_final<<<1, 256, 0, stream>>>(rowent, inp_pos, counts, out_loss);
}

// Round 6
// 2329.929 us; speedup vs baseline: 11.7472x; 1.0942x over previous
//
#include <hip/hip_runtime.h>
#include <math.h>
#include <cstdint>

#define BB 32
#define LL 256
#define TT 8192     // B*L
#define DIN 256
#define WEDm 200
#define PEDm 56
#define HH 512
#define G4 2048
#define MM 1024
#define EE 100
#define NTAGS 16

// ---------------- K1: embedding concat ----------------
__global__ void k_embed(const int* __restrict__ word, const int* __restrict__ posi,
                        const float* __restrict__ wemb, const float* __restrict__ pemb,
                        float* __restrict__ X) {
  int t = blockIdx.x;
  int c = threadIdx.x * 4;
  float4 v;
  if (c < WEDm) {
    int w = word[t];
    v = *(const float4*)(wemb + (size_t)w * WEDm + c);
  } else {
    int p = posi[t];
    v = *(const float4*)(pemb + (size_t)p * PEDm + (c - WEDm));
  }
  *(float4*)(X + (size_t)t * DIN + c) = v;
}

// ---------------- K2: C = A@W + bias (f32 tiled) ----------------
__global__ __launch_bounds__(256) void k_gemm_bias(const float* __restrict__ A,
    const float* __restrict__ W, const float* __restrict__ bias,
    float* __restrict__ C, int Mm, int Nn, int Kk) {
  __shared__ float As[16][68];
  __shared__ float Bs[16][64];
  int tid = threadIdx.x;
  int tx = tid & 15, ty = tid >> 4;
  int row0 = blockIdx.y * 64, col0 = blockIdx.x * 64;
  float acc[4][4] = {};
  for (int k0 = 0; k0 < Kk; k0 += 16) {
    int r = tid >> 2, c = (tid & 3) * 4;
    float4 av = *(const float4*)(A + (size_t)(row0 + r) * Kk + k0 + c);
    As[c + 0][r] = av.x; As[c + 1][r] = av.y; As[c + 2][r] = av.z; As[c + 3][r] = av.w;
    int r2 = tid >> 4, c2 = (tid & 15) * 4;
    float4 bv = *(const float4*)(W + (size_t)(k0 + r2) * Nn + col0 + c2);
    *(float4*)(&Bs[r2][c2]) = bv;
    __syncthreads();
#pragma unroll
    for (int kk = 0; kk < 16; ++kk) {
      float4 a4 = *(const float4*)(&As[kk][ty * 4]);
      float4 b4 = *(const float4*)(&Bs[kk][tx * 4]);
      float a[4] = {a4.x, a4.y, a4.z, a4.w};
      float b[4] = {b4.x, b4.y, b4.z, b4.w};
#pragma unroll
      for (int i = 0; i < 4; ++i)
#pragma unroll
        for (int j = 0; j < 4; ++j)
          acc[i][j] += a[i] * b[j];
    }
    __syncthreads();
  }
#pragma unroll
  for (int i = 0; i < 4; ++i) {
    int row = row0 + ty * 4 + i;
#pragma unroll
    for (int j = 0; j < 4; ++j) {
      int col = col0 + tx * 4 + j;
      C[(size_t)row * Nn + col] = acc[i][j] + bias[col];
    }
  }
}

// ---------------- DPP helper: rotate-add within row16 ----------------
template <int N>
__device__ __forceinline__ float ror_add(float x) {
  int xi = __float_as_int(x);
  int yi = __builtin_amdgcn_update_dpp(xi, xi, 0x100 + N, 0xF, 0xF, false);
  return x + __int_as_float(yi);
}

__device__ __forceinline__ float sigm(float x) { return 1.f / (1.f + __expf(-x)); }

// ---------------- K3: LSTM, 256 WGs = dir(2) x bgroup(4x8b) x ugroup(32x16u) ----
// 2-D decomposition: each WG needs only h[8 batches][512] = 16KB/step broadcast.
// Wh register-resident (64 VGPR). Per-WG flag slots, 32-wide poll, fence-free
// MALL protocol (relaxed agent atomics, vmcnt(0) drain before flag publish).
__global__ __launch_bounds__(512, 1) void k_lstm6(
    const float* __restrict__ Whf, const float* __restrict__ Whb,
    const float* __restrict__ GXfp, const float* __restrict__ GXbp,
    const float* __restrict__ maskp, float* __restrict__ Hbuf,
    float* __restrict__ ctx, int* __restrict__ flags) {
  extern __shared__ float lds[];
  float* Wtmp = lds;                // init only: [16 cols][512] (32KB)
  float* Hs   = lds;                // [8 b][516] overlays Wtmp after reg copy
  float* part = lds + 8 * 516;      // [2][64 lc][12]
  const int tid = threadIdx.x;
  const int wg  = blockIdx.x;
  const int dir = wg & 1;
  const int bg  = (wg >> 1) & 3;    // batch group: 8 batches
  const int ug  = wg >> 3;          // unit group 0..31: 16 units
  const int j0  = ug * 16;
  const int b0  = bg * 8;
  const float* Wh = dir ? Whb : Whf;
  const float* GX = dir ? GXbp : GXfp;

  const int ks = tid & 31;               // k lane: k = 4*ks + 128*j
  const int cq = tid >> 5;               // col group 0..15 (4 local cols each)
  const int uu = tid & 15, bloc = tid >> 4; // combine map (tid<128)

  // ---- stage Wh (64 cols x 512) into regs via 4 LDS chunks of 16 cols ----
  // local col lc = q*16 + u (q = gate 0..3, u = unit 0..15); chunk cc = gate q.
  float4 wreg[4][4];
#pragma unroll
  for (int cc = 0; cc < 4; ++cc) {
    for (int i = tid; i < 16 * 512; i += 512) {
      int c = i >> 9, k = i & 511;
      Wtmp[c * 512 + k] = Wh[(size_t)k * G4 + cc * HH + j0 + c];
    }
    __syncthreads();
    if ((cq >> 2) == cc) {
      int cbase = (cq & 3) * 4;
#pragma unroll
      for (int ci = 0; ci < 4; ++ci)
#pragma unroll
        for (int j = 0; j < 4; ++j)
          wreg[ci][j] = *(const float4*)(Wtmp + (cbase + ci) * 512 + 4 * ks + 128 * j);
    }
    __syncthreads();
  }

  // ---- zero my h slice (parity 0) via relaxed agent stores; publish ----
  if (tid < 128) {
    __hip_atomic_store(&Hbuf[(size_t)(0 * 2 + dir) * 16384 + (b0 + bloc) * HH + j0 + uu],
                       0.f, __ATOMIC_RELAXED, __HIP_MEMORY_SCOPE_AGENT);
  }
  asm volatile("s_waitcnt vmcnt(0)" ::: "memory");
  __syncthreads();
  if (tid == 0)
    __hip_atomic_store(&flags[wg], 1, __ATOMIC_RELAXED, __HIP_MEMORY_SCOPE_AGENT);

  float cstate = 0.f;
  int par = 0;

  for (int s = 0; s < LL; ++s) {
    const int t = dir ? (LL - 1 - s) : s;

    // ---- prefetch GX + mask (plain cached loads, independent of h) ----
    float gx0 = 0.f, gx1 = 0.f, gx2 = 0.f, gx3 = 0.f, mval = 0.f;
    if (tid < 128) {
      const float* gp = GX + ((size_t)((b0 + bloc) * LL + t)) * G4 + j0 + uu;
      gx0 = gp[0]; gx1 = gp[512]; gx2 = gp[1024]; gx3 = gp[1536];
      mval = maskp[(b0 + bloc) * LL + t];
    }

    // ---- poll: lane l waits for producer (dir, bg, ug=l) to reach step s ----
    if (tid < 32) {
      int it = 0;
      while (__hip_atomic_load(&flags[(tid * 4 + bg) * 2 + dir], __ATOMIC_RELAXED,
                               __HIP_MEMORY_SCOPE_AGENT) < s + 1) {
        __builtin_amdgcn_s_sleep(1);
        if (++it > (1 << 20)) break;   // hang guard
      }
    }
    __syncthreads();
    __builtin_amdgcn_sched_barrier(0);

    // ---- load h[par][my 8 batches] (16KB) via relaxed 8B loads -> LDS ----
    {
      const unsigned long long* hb64 =
          (const unsigned long long*)(Hbuf + (size_t)(par * 2 + dir) * 16384 + b0 * HH);
      unsigned long long hv[4];
#pragma unroll
      for (int m = 0; m < 4; ++m)
        hv[m] = __hip_atomic_load(&hb64[tid + 512 * m], __ATOMIC_RELAXED,
                                  __HIP_MEMORY_SCOPE_AGENT);
#pragma unroll
      for (int m = 0; m < 4; ++m) {
        int f = 2 * (tid + 512 * m);
        int b = f >> 9, k = f & 511;
        *(float2*)(&Hs[b * 516 + k]) = *(float2*)(&hv[m]);
      }
    }
    __syncthreads();

    // ---- 4x8 register-tiled matvec; Wh from regs, h from LDS ----
    float acc[4][8];
#pragma unroll
    for (int ci = 0; ci < 4; ++ci)
#pragma unroll
      for (int bi = 0; bi < 8; ++bi) acc[ci][bi] = 0.f;
    {
      const float* hp = Hs + 4 * ks;
#pragma unroll
      for (int j = 0; j < 4; ++j) {
        const int ko = 128 * j;
        float4 h4[8];
#pragma unroll
        for (int bi = 0; bi < 8; ++bi) h4[bi] = *(const float4*)(hp + bi * 516 + ko);
#pragma unroll
        for (int ci = 0; ci < 4; ++ci) {
          float4 w = wreg[ci][j];
#pragma unroll
          for (int bi = 0; bi < 8; ++bi) {
            float4 h = h4[bi];
            acc[ci][bi] += w.x * h.x + w.y * h.y + w.z * h.z + w.w * h.w;
          }
        }
      }
    }
    // ---- reduce over ks within row16 (ror-allreduce), 2 partials ----
#pragma unroll
    for (int ci = 0; ci < 4; ++ci)
#pragma unroll
      for (int bi = 0; bi < 8; ++bi) {
        float v = acc[ci][bi];
        v = ror_add<1>(v); v = ror_add<2>(v); v = ror_add<4>(v); v = ror_add<8>(v);
        acc[ci][bi] = v;
      }
    if ((ks & 15) == 0) {
      const int ph = ks >> 4;
      float* dst = part + ph * 768 + (cq * 4) * 12;
#pragma unroll
      for (int ci = 0; ci < 4; ++ci) {
        *(float4*)(dst + ci * 12 + 0) = make_float4(acc[ci][0], acc[ci][1], acc[ci][2], acc[ci][3]);
        *(float4*)(dst + ci * 12 + 4) = make_float4(acc[ci][4], acc[ci][5], acc[ci][6], acc[ci][7]);
      }
    }
    __syncthreads();

    // ---- gate combine (tid<128): unit uu (of 16), local batch bloc (of 8) ----
    float hn = 0.f;
    if (tid < 128) {
      float pre[4];
#pragma unroll
      for (int q = 0; q < 4; ++q) {
        int lc = q * 16 + uu;
        pre[q] = part[lc * 12 + bloc] + part[768 + lc * 12 + bloc];
      }
      pre[0] += gx0; pre[1] += gx1; pre[2] += gx2; pre[3] += gx3;
      float gi = sigm(pre[0]);
      float gf = sigm(pre[1]);
      float gg = tanhf(pre[2]);
      float go = sigm(pre[3]);
      float cnew = gf * cstate + gi * gg;
      float hnew = go * tanhf(cnew);
      float hold = Hs[bloc * 516 + j0 + uu];
      hn = hnew * mval + hold * (1.f - mval);
      cstate = cnew * mval + cstate * (1.f - mval);
      __hip_atomic_store(&Hbuf[(size_t)((par ^ 1) * 2 + dir) * 16384 + (b0 + bloc) * HH + j0 + uu],
                         hn, __ATOMIC_RELAXED, __HIP_MEMORY_SCOPE_AGENT);
    }
    asm volatile("s_waitcnt vmcnt(0)" ::: "memory");
    __syncthreads();
    if (tid == 0)
      __hip_atomic_store(&flags[wg], s + 2, __ATOMIC_RELAXED, __HIP_MEMORY_SCOPE_AGENT);
    // ctx store off the critical publish path
    if (tid < 128)
      ctx[((size_t)((b0 + bloc) * LL + t)) * (2 * HH) + dir * HH + j0 + uu] = hn;
    par ^= 1;
  }
}

__global__ void k_init0(int* __restrict__ flags) { flags[threadIdx.x] = 0; }

// ---------------- K4: tag histogram + stable compaction ----------------
__global__ void k_zero16(int* counts) { if (threadIdx.x < 16) counts[threadIdx.x] = 0; }

__global__ void k_count(const int* __restrict__ posi, int* __restrict__ counts) {
  int t = blockIdx.x * 256 + threadIdx.x;
  if (t < TT) atomicAdd(&counts[posi[t]], 1);
}

__global__ void k_prefix(const int* __restrict__ counts, int* __restrict__ offs) {
  if (threadIdx.x == 0) {
    int a = 0;
    for (int p = 0; p < NTAGS; ++p) { offs[p] = a; a += counts[p]; }
    offs[NTAGS] = a;
  }
}

__global__ __launch_bounds__(256) void k_compact(const int* __restrict__ posi,
    const int* __restrict__ offs, int* __restrict__ idxlist) {
  int p = blockIdx.x, tid = threadIdx.x;
  __shared__ int sc[256];
  __shared__ int sbase;
  if (tid == 0) sbase = offs[p];
  __syncthreads();
  for (int c0 = 0; c0 < TT; c0 += 256) {
    int t = c0 + tid;
    int f = (posi[t] == p) ? 1 : 0;
    int v = f;
    sc[tid] = v;
    __syncthreads();
    for (int o = 1; o < 256; o <<= 1) {
      int add = (tid >= o) ? sc[tid - o] : 0;
      __syncthreads();
      v += add;
      sc[tid] = v;
      __syncthreads();
    }
    int total = sc[255];
    int base = sbase;
    if (f) idxlist[base + v - 1] = t;
    __syncthreads();
    if (tid == 0) sbase = base + total;
    __syncthreads();
  }
}

// ---------------- K4b: gather per-tag psr rows ----------------
__global__ void k_ptbl(const int* __restrict__ wtbl, const float* __restrict__ psrw,
                       float* __restrict__ Ptbl) {
  int i = blockIdx.x * 256 + threadIdx.x;
  int total = NTAGS * MM * EE;
  for (; i < total; i += gridDim.x * 256) {
    int p = i / (MM * EE);
    int rem = i - p * (MM * EE);
    int r = rem / EE;
    int e = rem - r * EE;
    Ptbl[i] = psrw[(size_t)wtbl[p * MM + r] * EE + e];
  }
}

// ---------------- K5: grouped decoder GEMM ----------------
__global__ __launch_bounds__(256) void k_decgemm(const float* __restrict__ ctxb,
    const float* __restrict__ decW, const float* __restrict__ decb,
    const int* __restrict__ counts, const int* __restrict__ offs,
    const int* __restrict__ idxlist, float* __restrict__ Z) {
  int p = blockIdx.z;
  int n = counts[p];
  int r0 = blockIdx.y * 64;
  if (r0 >= n) return;
  int col0 = blockIdx.x * 64;
  __shared__ float As[16][68];
  __shared__ float Bs[16][64];
  __shared__ int rows[64];
  int tid = threadIdx.x;
  if (tid < 64) {
    int r = r0 + tid;
    rows[tid] = idxlist[offs[p] + (r < n ? r : 0)];
  }
  __syncthreads();
  const float* W = decW + (size_t)p * MM * MM;
  float acc[4][4] = {};
  for (int k0 = 0; k0 < MM; k0 += 16) {
    int r = tid >> 2, c = (tid & 3) * 4;
    float4 av = *(const float4*)(ctxb + (size_t)rows[r] * MM + k0 + c);
    As[c + 0][r] = av.x; As[c + 1][r] = av.y; As[c + 2][r] = av.z; As[c + 3][r] = av.w;
    int r2 = tid >> 4, c2 = (tid & 15) * 4;
    float4 bv = *(const float4*)(W + (size_t)(k0 + r2) * MM + col0 + c2);
    *(float4*)(&Bs[r2][c2]) = bv;
    __syncthreads();
#pragma unroll
    for (int kk = 0; kk < 16; ++kk) {
      float4 a4 = *(const float4*)(&As[kk][(tid >> 4) * 4]);
      float4 b4 = *(const float4*)(&Bs[kk][(tid & 15) * 4]);
      float a[4] = {a4.x, a4.y, a4.z, a4.w};
      float b[4] = {b4.x, b4.y, b4.z, b4.w};
#pragma unroll
      for (int i = 0; i < 4; ++i)
#pragma unroll
        for (int j = 0; j < 4; ++j)
          acc[i][j] += a[i] * b[j];
    }
    __syncthreads();
  }
  int tx = tid & 15, ty = tid >> 4;
#pragma unroll
  for (int i = 0; i < 4; ++i) {
    int r = r0 + ty * 4 + i;
    if (r < n) {
      int tok = rows[ty * 4 + i];
#pragma unroll
      for (int j = 0; j < 4; ++j) {
        int col = col0 + tx * 4 + j;
        Z[(size_t)tok * MM + col] = acc[i][j] + decb[p * MM + col];
      }
    }
  }
}

// ---------------- K6: per-token softmax / entropy / gumbel argmax ----------------
__global__ __launch_bounds__(256) void k_softmax(
    const float* __restrict__ Z, const float* __restrict__ gum,
    const int* __restrict__ posi, const int* __restrict__ wflat,
    const int* __restrict__ wtbl, float* __restrict__ SPT,
    float* __restrict__ rowent, int* __restrict__ avoidb,
    float* __restrict__ out_word, float* __restrict__ out_mask,
    float* __restrict__ out_pri) {
  __shared__ float red[256];
  __shared__ float redv[256];
  __shared__ int redi[256];
  int t = blockIdx.x, tid = threadIdx.x;
  float z[4];
#pragma unroll
  for (int i = 0; i < 4; ++i) z[i] = Z[(size_t)t * MM + tid + 256 * i];
  float mx = fmaxf(fmaxf(z[0], z[1]), fmaxf(z[2], z[3]));
  red[tid] = mx; __syncthreads();
  for (int o = 128; o > 0; o >>= 1) { if (tid < o) red[tid] = fmaxf(red[tid], red[tid + o]); __syncthreads(); }
  mx = red[0]; __syncthreads();
  float se = 0.f;
#pragma unroll
  for (int i = 0; i < 4; ++i) se += expf(z[i] - mx);
  red[tid] = se; __syncthreads();
  for (int o = 128; o > 0; o >>= 1) { if (tid < o) red[tid] += red[tid + o]; __syncthreads(); }
  float lse = logf(red[0]); __syncthreads();
  float lp[4]; float ent = 0.f;
#pragma unroll
  for (int i = 0; i < 4; ++i) { lp[i] = z[i] - mx - lse; ent -= lp[i] * expf(lp[i]); }
  red[tid] = ent; __syncthreads();
  for (int o = 128; o > 0; o >>= 1) { if (tid < o) red[tid] += red[tid + o]; __syncthreads(); }
  float enttot = red[0]; __syncthreads();
  float y[4];
#pragma unroll
  for (int i = 0; i < 4; ++i) {
    float u = gum[(size_t)t * MM + tid + 256 * i];
    float g = -logf(-logf(u + 1e-10f) + 1e-10f);
    y[i] = lp[i] + g;
  }
  float bv = y[0]; int bi = tid;
#pragma unroll
  for (int i = 1; i < 4; ++i) { int j = tid + 256 * i; if (y[i] > bv) { bv = y[i]; bi = j; } }
  redv[tid] = bv; redi[tid] = bi; __syncthreads();
  for (int o = 128; o > 0; o >>= 1) {
    if (tid < o) {
      float v2 = redv[tid + o]; int i2 = redi[tid + o];
      if (v2 > redv[tid] || (v2 == redv[tid] && i2 < redi[tid])) { redv[tid] = v2; redi[tid] = i2; }
    }
    __syncthreads();
  }
  float ymax = redv[0]; int amax = redi[0]; __syncthreads();
  float e[4]; float s2 = 0.f;
#pragma unroll
  for (int i = 0; i < 4; ++i) { e[i] = expf(y[i] - ymax); s2 += e[i]; }
  red[tid] = s2; __syncthreads();
  for (int o = 128; o > 0; o >>= 1) { if (tid < o) red[tid] += red[tid + o]; __syncthreads(); }
  float inv = 1.f / red[0];
#pragma unroll
  for (int i = 0; i < 4; ++i) SPT[(size_t)t * MM + tid + 256 * i] = e[i] * inv;
  if (tid == 0) {
    int p = posi[t];
    int widx = wtbl[p * MM + amax];
    int wf = wflat[t];
    int avoid = (widx == wf) ? 1 : 0;
    avoidb[t] = avoid;
    out_word[t] = (float)(avoid ? 0 : widx);
    out_mask[t] = 1.0f;
    out_pri[t] = (p < 4) ? 1.0f : 0.0f;
    rowent[t] = enttot;
  }
}

// ---------------- K7: grouped emb GEMM ----------------
__global__ __launch_bounds__(256) void k_embgemm(const float* __restrict__ SPT,
    const float* __restrict__ Ptbl, const float* __restrict__ psrw,
    const int* __restrict__ counts, const int* __restrict__ offs,
    const int* __restrict__ idxlist, const int* __restrict__ avoidb,
    float* __restrict__ out_emb) {
  int p = blockIdx.y;
  int n = counts[p];
  int r0 = blockIdx.x * 64;
  if (r0 >= n) return;
  __shared__ float As[16][68];
  __shared__ float Bs[16][132];
  __shared__ int rows[64];
  int tid = threadIdx.x;
  if (tid < 64) rows[tid] = idxlist[offs[p] + ((r0 + tid) < n ? (r0 + tid) : 0)];
  __syncthreads();
  const float* P = Ptbl + (size_t)p * MM * EE;
  int tx = tid & 31, ty = tid >> 5;
  float acc[8][4] = {};
  for (int k0 = 0; k0 < MM; k0 += 16) {
    int r = tid >> 2, c = (tid & 3) * 4;
    float4 av = *(const float4*)(SPT + (size_t)rows[r] * MM + k0 + c);
    As[c + 0][r] = av.x; As[c + 1][r] = av.y; As[c + 2][r] = av.z; As[c + 3][r] = av.w;
    int r2 = tid >> 4;
    int c2 = (tid & 15) * 8;
    float4 b0 = make_float4(0.f, 0.f, 0.f, 0.f), b1 = make_float4(0.f, 0.f, 0.f, 0.f);
    if (c2 + 3 < EE) b0 = *(const float4*)(P + (size_t)(k0 + r2) * EE + c2);
    if (c2 + 7 < EE) b1 = *(const float4*)(P + (size_t)(k0 + r2) * EE + c2 + 4);
    *(float4*)(&Bs[r2][c2]) = b0;
    *(float4*)(&Bs[r2][c2 + 4]) = b1;
    __syncthreads();
#pragma unroll
    for (int kk = 0; kk < 16; ++kk) {
      float4 b4 = *(const float4*)(&Bs[kk][tx * 4]);
      float4 a0 = *(const float4*)(&As[kk][ty * 8]);
      float4 a1 = *(const float4*)(&As[kk][ty * 8 + 4]);
      float a[8] = {a0.x, a0.y, a0.z, a0.w, a1.x, a1.y, a1.z, a1.w};
#pragma unroll
      for (int ri = 0; ri < 8; ++ri) {
        acc[ri][0] += a[ri] * b4.x; acc[ri][1] += a[ri] * b4.y;
        acc[ri][2] += a[ri] * b4.z; acc[ri][3] += a[ri] * b4.w;
      }
    }
    __syncthreads();
  }
#pragma unroll
  for (int ri = 0; ri < 8; ++ri) {
    int r = ty * 8 + ri;
    if (r0 + r < n) {
      int tok = rows[r];
      int av = avoidb[tok];
#pragma unroll
      for (int j = 0; j < 4; ++j) {
        int col = tx * 4 + j;
        if (col < EE) {
          float v = av ? psrw[col] : acc[ri][j];
          out_emb[(size_t)tok * EE + col] = v;
        }
      }
    }
  }
}

// ---------------- K8: deterministic entropy-loss reduction ----------------
__global__ __launch_bounds__(256) void k_final(const float* __restrict__ rowent,
    const int* __restrict__ posi, const int* __restrict__ counts,
    float* __restrict__ out_loss) {
  __shared__ float red[256];
  int tid = threadIdx.x;
  float s = 0.f;
  for (int t = tid; t < TT; t += 256) {
    int p = posi[t];
    float denom = fmaxf((float)counts[p] * (float)MM, 1.0f);
    s += rowent[t] / denom;
  }
  red[tid] = s; __syncthreads();
  for (int o = 128; o > 0; o >>= 1) { if (tid < o) red[tid] += red[tid + o]; __syncthreads(); }
  if (tid == 0) out_loss[0] = -red[0] * 0.01f;
}

// ---------------- launcher ----------------
extern "C" void kernel_launch(void* const* d_in, const int* in_sizes, int n_in,
                              void* d_out, int out_size, void* d_ws, size_t ws_size,
                              hipStream_t stream) {
  const int*   inp_word = (const int*)d_in[0];
  const int*   inp_pos  = (const int*)d_in[1];
  const float* inp_mask = (const float*)d_in[2];
  const float* gum      = (const float*)d_in[3];
  const float* wemb     = (const float*)d_in[4];
  const float* pemb     = (const float*)d_in[5];
  const float* Wx_f     = (const float*)d_in[6];
  const float* Wh_f     = (const float*)d_in[7];
  const float* b_f      = (const float*)d_in[8];
  const float* Wx_b     = (const float*)d_in[9];
  const float* Wh_b     = (const float*)d_in[10];
  const float* b_b      = (const float*)d_in[11];
  const float* decW     = (const float*)d_in[12];
  const float* decb     = (const float*)d_in[13];
  const int*   wtbl     = (const int*)d_in[14];
  const float* psrw     = (const float*)d_in[15];

  float* out_word = (float*)d_out;
  float* out_emb  = out_word + TT;
  float* out_mask = out_emb + (size_t)TT * EE;
  float* out_pri  = out_mask + TT;
  float* out_loss = out_pri + TT;

  float* ws = (float*)d_ws;
  float* X      = ws;
  float* GXf    = X + (size_t)TT * DIN;
  float* GXb    = GXf + (size_t)TT * G4;
  float* ctxb   = GXb + (size_t)TT * G4;
  float* Hbuf   = ctxb + (size_t)TT * MM;
  float* rowent = Hbuf + 2 * 2 * BB * HH;
  int* avoidb   = (int*)(rowent + TT);
  int* counts   = avoidb + TT;
  int* offs     = counts + 16;
  int* idxlist  = offs + 32;
  int* flags    = idxlist + TT;
  float* Z    = GXf;   // reuse: GX dead after LSTM
  float* SPT  = Z;     // in-place row rewrite in k_softmax
  float* Ptbl = GXb;   // reuse

  k_embed<<<TT, 64, 0, stream>>>(inp_word, inp_pos, wemb, pemb, X);
  k_gemm_bias<<<dim3(G4 / 64, TT / 64), 256, 0, stream>>>(X, Wx_f, b_f, GXf, TT, G4, DIN);
  k_gemm_bias<<<dim3(G4 / 64, TT / 64), 256, 0, stream>>>(X, Wx_b, b_b, GXb, TT, G4, DIN);

  k_init0<<<1, 256, 0, stream>>>(flags);
  {
    const int ldsz = 32768;  // max(Wtmp 32KB, Hs+part ~22.7KB)
    hipFuncSetAttribute((const void*)k_lstm6,
                        hipFuncAttributeMaxDynamicSharedMemorySize, ldsz);
    k_lstm6<<<256, 512, ldsz, stream>>>(Wh_f, Wh_b, GXf, GXb, inp_mask, Hbuf, ctxb, flags);
  }

  k_zero16<<<1, 64, 0, stream>>>(counts);
  k_count<<<TT / 256, 256, 0, stream>>>(inp_pos, counts);
  k_prefix<<<1, 64, 0, stream>>>(counts, offs);
  k_compact<<<NTAGS, 256, 0, stream>>>(inp_pos, offs, idxlist);
  k_ptbl<<<1024, 256, 0, stream>>>(wtbl, psrw, Ptbl);
  k_decgemm<<<dim3(MM / 64, TT / 64, NTAGS), 256, 0, stream>>>(ctxb, decW, decb, counts, offs, idxlist, Z);
  k_softmax<<<TT, 256, 0, stream>>>(Z, gum, inp_pos, inp_word, wtbl, SPT, rowent, avoidb,
                                    out_word, out_mask, out_pri);
  k_embgemm<<<dim3(TT / 64, NTAGS), 256, 0, stream>>>(SPT, Ptbl, psrw, counts, offs, idxlist,
                                                      avoidb, out_emb);
  k_final<<<1, 256, 0, stream>>>(rowent, inp_pos, counts, out_loss);
}

// Round 7
// 2123.067 us; speedup vs baseline: 12.8918x; 1.0974x over previous
//
#include <hip/hip_runtime.h>
#include <math.h>
#include <cstdint>

#define BB 32
#define LL 256
#define TT 8192     // B*L
#define DIN 256
#define WEDm 200
#define PEDm 56
#define HH 512
#define G4 2048
#define MM 1024
#define EE 100
#define NTAGS 16

// ---------------- K1: embedding concat ----------------
__global__ void k_embed(const int* __restrict__ word, const int* __restrict__ posi,
                        const float* __restrict__ wemb, const float* __restrict__ pemb,
                        float* __restrict__ X) {
  int t = blockIdx.x;
  int c = threadIdx.x * 4;
  float4 v;
  if (c < WEDm) {
    int w = word[t];
    v = *(const float4*)(wemb + (size_t)w * WEDm + c);
  } else {
    int p = posi[t];
    v = *(const float4*)(pemb + (size_t)p * PEDm + (c - WEDm));
  }
  *(float4*)(X + (size_t)t * DIN + c) = v;
}

// ---------------- K2: fused dual GEMM  GX{f,b} = X @ Wx{f,b} + b{f,b} ----------------
// 128x128 tile, 8x8 micro, K=256. col0 < 2048 -> f half, else b half.
__global__ __launch_bounds__(256) void k_gemm2(const float* __restrict__ X,
    const float* __restrict__ Wf, const float* __restrict__ Wb,
    const float* __restrict__ bf, const float* __restrict__ bb,
    float* __restrict__ GXf, float* __restrict__ GXb) {
  __shared__ float As[16][132];
  __shared__ float Bs[16][132];
  const int tid = threadIdx.x;
  const int row0 = blockIdx.y * 128;
  const int col0 = blockIdx.x * 128;     // 0..4095
  const int isB = (col0 >= G4) ? 1 : 0;
  const float* W = isB ? Wb : Wf;
  const float* bias = isB ? bb : bf;
  const int wcol0 = col0 - (isB ? G4 : 0);
  const int ar = tid >> 1, ac = (tid & 1) * 8;
  const int br = tid >> 4, bc = (tid & 15) * 8;
  const int ty = tid >> 4, tx = tid & 15;
  float acc[8][8] = {};
  for (int k0 = 0; k0 < DIN; k0 += 16) {
    float4 a0 = *(const float4*)(X + (size_t)(row0 + ar) * DIN + k0 + ac);
    float4 a1 = *(const float4*)(X + (size_t)(row0 + ar) * DIN + k0 + ac + 4);
    float4 b0 = *(const float4*)(W + (size_t)(k0 + br) * G4 + wcol0 + bc);
    float4 b1 = *(const float4*)(W + (size_t)(k0 + br) * G4 + wcol0 + bc + 4);
    As[ac + 0][ar] = a0.x; As[ac + 1][ar] = a0.y; As[ac + 2][ar] = a0.z; As[ac + 3][ar] = a0.w;
    As[ac + 4][ar] = a1.x; As[ac + 5][ar] = a1.y; As[ac + 6][ar] = a1.z; As[ac + 7][ar] = a1.w;
    *(float4*)(&Bs[br][bc]) = b0;
    *(float4*)(&Bs[br][bc + 4]) = b1;
    __syncthreads();
#pragma unroll
    for (int kk = 0; kk < 16; ++kk) {
      float4 aa0 = *(const float4*)(&As[kk][ty * 8]);
      float4 aa1 = *(const float4*)(&As[kk][ty * 8 + 4]);
      float4 bb0 = *(const float4*)(&Bs[kk][tx * 8]);
      float4 bb1 = *(const float4*)(&Bs[kk][tx * 8 + 4]);
      float a[8] = {aa0.x, aa0.y, aa0.z, aa0.w, aa1.x, aa1.y, aa1.z, aa1.w};
      float b[8] = {bb0.x, bb0.y, bb0.z, bb0.w, bb1.x, bb1.y, bb1.z, bb1.w};
#pragma unroll
      for (int i = 0; i < 8; ++i)
#pragma unroll
        for (int j = 0; j < 8; ++j)
          acc[i][j] += a[i] * b[j];
    }
    __syncthreads();
  }
  float* OUT = isB ? GXb : GXf;
#pragma unroll
  for (int i = 0; i < 8; ++i) {
    int row = row0 + ty * 8 + i;
#pragma unroll
    for (int j = 0; j < 8; ++j) {
      int col = wcol0 + tx * 8 + j;
      OUT[(size_t)row * G4 + col] = acc[i][j] + bias[col];
    }
  }
}

// ---------------- DPP helper: rotate-add within row16 ----------------
template <int N>
__device__ __forceinline__ float ror_add(float x) {
  int xi = __float_as_int(x);
  int yi = __builtin_amdgcn_update_dpp(xi, xi, 0x100 + N, 0xF, 0xF, false);
  return x + __int_as_float(yi);
}

__device__ __forceinline__ float sigm(float x) { return 1.f / (1.f + __expf(-x)); }

// ---------------- init Hpair slabs: slab0 = (h=0, seq=0); slab1 = invalid ----------------
__global__ void k_initH(unsigned long long* __restrict__ Hpair) {
  int i = blockIdx.x * 256 + threadIdx.x;           // 65536 total
  Hpair[i] = (i < 32768) ? 0ull : 0xFFFFFFFF00000000ull;
}

// ---------------- K3: LSTM, 256 WGs = dir(2) x bgroup(4x8b) x ugroup(32x16u) ----------
// Seq-tagged dataflow: each h word is (seq<<32)|f32bits, stored/loaded with 8B
// relaxed agent atomics. Consumers poll data words directly (per-word seq check,
// masked retry) -- no flags, no vmcnt drain on the producer side. 2-slab parity.
__global__ __launch_bounds__(512, 1) void k_lstm7(
    const float* __restrict__ Whf, const float* __restrict__ Whb,
    const float* __restrict__ GXfp, const float* __restrict__ GXbp,
    const float* __restrict__ maskp, unsigned long long* __restrict__ Hpair,
    float* __restrict__ ctx) {
  extern __shared__ float lds[];
  float* Wtmp = lds;                // init only: [16 cols][512] (32KB)
  float* Hs   = lds;                // [8 b][516] overlays Wtmp after reg copy
  float* part = lds + 8 * 516;      // [2][64 lc][12]
  const int tid = threadIdx.x;
  const int wg  = blockIdx.x;
  const int dir = wg & 1;
  const int bg  = (wg >> 1) & 3;    // batch group: 8 batches
  const int ug  = wg >> 3;          // unit group 0..31: 16 units
  const int j0  = ug * 16;
  const int b0  = bg * 8;
  const float* Wh = dir ? Whb : Whf;
  const float* GX = dir ? GXbp : GXfp;

  const int ks = tid & 31;               // k lane: k = 4*ks + 128*j
  const int cq = tid >> 5;               // col group 0..15 (4 local cols each)
  const int uu = tid & 15, bloc = tid >> 4; // combine map (tid<128)

  // ---- stage Wh (64 cols x 512) into regs via 4 LDS chunks of 16 cols ----
  float4 wreg[4][4];
#pragma unroll
  for (int cc = 0; cc < 4; ++cc) {
    for (int i = tid; i < 16 * 512; i += 512) {
      int c = i >> 9, k = i & 511;
      Wtmp[c * 512 + k] = Wh[(size_t)k * G4 + cc * HH + j0 + c];
    }
    __syncthreads();
    if ((cq >> 2) == cc) {
      int cbase = (cq & 3) * 4;
#pragma unroll
      for (int ci = 0; ci < 4; ++ci)
#pragma unroll
        for (int j = 0; j < 4; ++j)
          wreg[ci][j] = *(const float4*)(Wtmp + (cbase + ci) * 512 + 4 * ks + 128 * j);
    }
    __syncthreads();
  }

  float cstate = 0.f;

  for (int s = 0; s < LL; ++s) {
    const int t = dir ? (LL - 1 - s) : s;

    // ---- prefetch GX + mask (plain cached loads, independent of h) ----
    float gx0 = 0.f, gx1 = 0.f, gx2 = 0.f, gx3 = 0.f, mval = 0.f;
    if (tid < 128) {
      const float* gp = GX + ((size_t)((b0 + bloc) * LL + t)) * G4 + j0 + uu;
      gx0 = gp[0]; gx1 = gp[512]; gx2 = gp[1024]; gx3 = gp[1536];
      mval = maskp[(b0 + bloc) * LL + t];
    }

    // ---- consumer: seq-checked pair loads of h_s (slab s&1) ----
    const unsigned long long* hb =
        Hpair + ((size_t)((s & 1) * 2 + dir) * 32 + b0) * 512;
    unsigned long long hv[8];
#pragma unroll
    for (int m = 0; m < 8; ++m)
      hv[m] = __hip_atomic_load(&hb[tid + 512 * m], __ATOMIC_RELAXED,
                                __HIP_MEMORY_SCOPE_AGENT);
    {
      const unsigned expect = (unsigned)s;
      int guard = 0;
      for (;;) {
        unsigned stale = 0u;
#pragma unroll
        for (int m = 0; m < 8; ++m)
          if ((unsigned)(hv[m] >> 32) != expect) stale |= (1u << m);
        if (!stale) break;
        if (++guard > (1 << 15)) break;   // hang guard
#pragma unroll
        for (int m = 0; m < 8; ++m)
          if (stale & (1u << m))
            hv[m] = __hip_atomic_load(&hb[tid + 512 * m], __ATOMIC_RELAXED,
                                      __HIP_MEMORY_SCOPE_AGENT);
      }
    }
#pragma unroll
    for (int m = 0; m < 8; ++m) {
      int f = tid + 512 * m;
      Hs[(f >> 9) * 516 + (f & 511)] = __uint_as_float((unsigned)hv[m]);
    }
    __syncthreads();

    // ---- 4x8 register-tiled matvec; Wh from regs, h from LDS ----
    float acc[4][8];
#pragma unroll
    for (int ci = 0; ci < 4; ++ci)
#pragma unroll
      for (int bi = 0; bi < 8; ++bi) acc[ci][bi] = 0.f;
    {
      const float* hp = Hs + 4 * ks;
#pragma unroll
      for (int j = 0; j < 4; ++j) {
        const int ko = 128 * j;
        float4 h4[8];
#pragma unroll
        for (int bi = 0; bi < 8; ++bi) h4[bi] = *(const float4*)(hp + bi * 516 + ko);
#pragma unroll
        for (int ci = 0; ci < 4; ++ci) {
          float4 w = wreg[ci][j];
#pragma unroll
          for (int bi = 0; bi < 8; ++bi) {
            float4 h = h4[bi];
            acc[ci][bi] += w.x * h.x + w.y * h.y + w.z * h.z + w.w * h.w;
          }
        }
      }
    }
    // ---- reduce over ks within row16 (ror-allreduce), 2 partials ----
#pragma unroll
    for (int ci = 0; ci < 4; ++ci)
#pragma unroll
      for (int bi = 0; bi < 8; ++bi) {
        float v = acc[ci][bi];
        v = ror_add<1>(v); v = ror_add<2>(v); v = ror_add<4>(v); v = ror_add<8>(v);
        acc[ci][bi] = v;
      }
    if ((ks & 15) == 0) {
      const int ph = ks >> 4;
      float* dst = part + ph * 768 + (cq * 4) * 12;
#pragma unroll
      for (int ci = 0; ci < 4; ++ci) {
        *(float4*)(dst + ci * 12 + 0) = make_float4(acc[ci][0], acc[ci][1], acc[ci][2], acc[ci][3]);
        *(float4*)(dst + ci * 12 + 4) = make_float4(acc[ci][4], acc[ci][5], acc[ci][6], acc[ci][7]);
      }
    }
    __syncthreads();

    // ---- gate combine (tid<128) + producer store (h_{s+1}, seq s+1) ----
    if (tid < 128) {
      float pre[4];
#pragma unroll
      for (int q = 0; q < 4; ++q) {
        int lc = q * 16 + uu;
        pre[q] = part[lc * 12 + bloc] + part[768 + lc * 12 + bloc];
      }
      pre[0] += gx0; pre[1] += gx1; pre[2] += gx2; pre[3] += gx3;
      float gi = sigm(pre[0]);
      float gf = sigm(pre[1]);
      float gg = tanhf(pre[2]);
      float go = sigm(pre[3]);
      float cnew = gf * cstate + gi * gg;
      float hnew = go * tanhf(cnew);
      float hold = Hs[bloc * 516 + j0 + uu];
      float hn = hnew * mval + hold * (1.f - mval);
      cstate = cnew * mval + cstate * (1.f - mval);
      unsigned long long pk = ((unsigned long long)(unsigned)(s + 1) << 32) |
                              (unsigned long long)__float_as_uint(hn);
      __hip_atomic_store(
          &Hpair[((size_t)(((s + 1) & 1) * 2 + dir) * 32 + (b0 + bloc)) * 512 + j0 + uu],
          pk, __ATOMIC_RELAXED, __HIP_MEMORY_SCOPE_AGENT);
      ctx[((size_t)((b0 + bloc) * LL + t)) * (2 * HH) + dir * HH + j0 + uu] = hn;
    }
    __syncthreads();   // protect Hs/part before next-iter staging
  }
}

// ---------------- K4: tag histogram + stable compaction ----------------
__global__ void k_zero16(int* counts) { if (threadIdx.x < 16) counts[threadIdx.x] = 0; }

__global__ void k_count(const int* __restrict__ posi, int* __restrict__ counts) {
  int t = blockIdx.x * 256 + threadIdx.x;
  if (t < TT) atomicAdd(&counts[posi[t]], 1);
}

__global__ void k_prefix(const int* __restrict__ counts, int* __restrict__ offs) {
  if (threadIdx.x == 0) {
    int a = 0;
    for (int p = 0; p < NTAGS; ++p) { offs[p] = a; a += counts[p]; }
    offs[NTAGS] = a;
  }
}

__global__ __launch_bounds__(256) void k_compact(const int* __restrict__ posi,
    const int* __restrict__ offs, int* __restrict__ idxlist) {
  int p = blockIdx.x, tid = threadIdx.x;
  __shared__ int sc[256];
  __shared__ int sbase;
  if (tid == 0) sbase = offs[p];
  __syncthreads();
  for (int c0 = 0; c0 < TT; c0 += 256) {
    int t = c0 + tid;
    int f = (posi[t] == p) ? 1 : 0;
    int v = f;
    sc[tid] = v;
    __syncthreads();
    for (int o = 1; o < 256; o <<= 1) {
      int add = (tid >= o) ? sc[tid - o] : 0;
      __syncthreads();
      v += add;
      sc[tid] = v;
      __syncthreads();
    }
    int total = sc[255];
    int base = sbase;
    if (f) idxlist[base + v - 1] = t;
    __syncthreads();
    if (tid == 0) sbase = base + total;
    __syncthreads();
  }
}

// ---------------- K4b: gather per-tag psr rows ----------------
__global__ void k_ptbl(const int* __restrict__ wtbl, const float* __restrict__ psrw,
                       float* __restrict__ Ptbl) {
  int i = blockIdx.x * 256 + threadIdx.x;
  int total = NTAGS * MM * EE;
  for (; i < total; i += gridDim.x * 256) {
    int p = i / (MM * EE);
    int rem = i - p * (MM * EE);
    int r = rem / EE;
    int e = rem - r * EE;
    Ptbl[i] = psrw[(size_t)wtbl[p * MM + r] * EE + e];
  }
}

// ---------------- K5: grouped decoder GEMM ----------------
__global__ __launch_bounds__(256) void k_decgemm(const float* __restrict__ ctxb,
    const float* __restrict__ decW, const float* __restrict__ decb,
    const int* __restrict__ counts, const int* __restrict__ offs,
    const int* __restrict__ idxlist, float* __restrict__ Z) {
  int p = blockIdx.z;
  int n = counts[p];
  int r0 = blockIdx.y * 64;
  if (r0 >= n) return;
  int col0 = blockIdx.x * 64;
  __shared__ float As[16][68];
  __shared__ float Bs[16][64];
  __shared__ int rows[64];
  int tid = threadIdx.x;
  if (tid < 64) {
    int r = r0 + tid;
    rows[tid] = idxlist[offs[p] + (r < n ? r : 0)];
  }
  __syncthreads();
  const float* W = decW + (size_t)p * MM * MM;
  float acc[4][4] = {};
  for (int k0 = 0; k0 < MM; k0 += 16) {
    int r = tid >> 2, c = (tid & 3) * 4;
    float4 av = *(const float4*)(ctxb + (size_t)rows[r] * MM + k0 + c);
    As[c + 0][r] = av.x; As[c + 1][r] = av.y; As[c + 2][r] = av.z; As[c + 3][r] = av.w;
    int r2 = tid >> 4, c2 = (tid & 15) * 4;
    float4 bv = *(const float4*)(W + (size_t)(k0 + r2) * MM + col0 + c2);
    *(float4*)(&Bs[r2][c2]) = bv;
    __syncthreads();
#pragma unroll
    for (int kk = 0; kk < 16; ++kk) {
      float4 a4 = *(const float4*)(&As[kk][(tid >> 4) * 4]);
      float4 b4 = *(const float4*)(&Bs[kk][(tid & 15) * 4]);
      float a[4] = {a4.x, a4.y, a4.z, a4.w};
      float b[4] = {b4.x, b4.y, b4.z, b4.w};
#pragma unroll
      for (int i = 0; i < 4; ++i)
#pragma unroll
        for (int j = 0; j < 4; ++j)
          acc[i][j] += a[i] * b[j];
    }
    __syncthreads();
  }
  int tx = tid & 15, ty = tid >> 4;
#pragma unroll
  for (int i = 0; i < 4; ++i) {
    int r = r0 + ty * 4 + i;
    if (r < n) {
      int tok = rows[ty * 4 + i];
#pragma unroll
      for (int j = 0; j < 4; ++j) {
        int col = col0 + tx * 4 + j;
        Z[(size_t)tok * MM + col] = acc[i][j] + decb[p * MM + col];
      }
    }
  }
}

// ---------------- K6: per-token softmax / entropy / gumbel argmax ----------------
// Trans-trimmed: ent = lse - sum((z-mx)*e)/se  (exp(lp) never computed);
// argmax over (z-mx)+g (lse shift uniform); 4 tree reductions.
__global__ __launch_bounds__(256) void k_softmax(
    const float* __restrict__ Z, const float* __restrict__ gum,
    const int* __restrict__ posi, const int* __restrict__ wflat,
    const int* __restrict__ wtbl, float* __restrict__ SPT,
    float* __restrict__ rowent, int* __restrict__ avoidb,
    float* __restrict__ out_word, float* __restrict__ out_mask,
    float* __restrict__ out_pri) {
  __shared__ float red[256];
  __shared__ float red2[256];
  __shared__ float redv[256];
  __shared__ int redi[256];
  int t = blockIdx.x, tid = threadIdx.x;
  float z[4];
#pragma unroll
  for (int i = 0; i < 4; ++i) z[i] = Z[(size_t)t * MM + tid + 256 * i];
  float mx = fmaxf(fmaxf(z[0], z[1]), fmaxf(z[2], z[3]));
  red[tid] = mx; __syncthreads();
  for (int o = 128; o > 0; o >>= 1) { if (tid < o) red[tid] = fmaxf(red[tid], red[tid + o]); __syncthreads(); }
  mx = red[0]; __syncthreads();
  float ev[4]; float se = 0.f, we = 0.f;
#pragma unroll
  for (int i = 0; i < 4; ++i) {
    float d = z[i] - mx;
    float e = expf(d);
    ev[i] = e; se += e; we += d * e;
  }
  red[tid] = se; red2[tid] = we; __syncthreads();
  for (int o = 128; o > 0; o >>= 1) {
    if (tid < o) { red[tid] += red[tid + o]; red2[tid] += red2[tid + o]; }
    __syncthreads();
  }
  float se_tot = red[0], we_tot = red2[0]; __syncthreads();
  float lse = logf(se_tot);
  float ent = lse - we_tot / se_tot;
  float y[4];
#pragma unroll
  for (int i = 0; i < 4; ++i) {
    float u = gum[(size_t)t * MM + tid + 256 * i];
    float g = -logf(-logf(u + 1e-10f) + 1e-10f);
    y[i] = (z[i] - mx) + g;
  }
  float bv = y[0]; int bi = tid;
#pragma unroll
  for (int i = 1; i < 4; ++i) { int j = tid + 256 * i; if (y[i] > bv) { bv = y[i]; bi = j; } }
  redv[tid] = bv; redi[tid] = bi; __syncthreads();
  for (int o = 128; o > 0; o >>= 1) {
    if (tid < o) {
      float v2 = redv[tid + o]; int i2 = redi[tid + o];
      if (v2 > redv[tid] || (v2 == redv[tid] && i2 < redi[tid])) { redv[tid] = v2; redi[tid] = i2; }
    }
    __syncthreads();
  }
  float ymax = redv[0]; int amax = redi[0]; __syncthreads();
  float e2[4]; float s2 = 0.f;
#pragma unroll
  for (int i = 0; i < 4; ++i) { e2[i] = expf(y[i] - ymax); s2 += e2[i]; }
  red[tid] = s2; __syncthreads();
  for (int o = 128; o > 0; o >>= 1) { if (tid < o) red[tid] += red[tid + o]; __syncthreads(); }
  float inv = 1.f / red[0];
#pragma unroll
  for (int i = 0; i < 4; ++i) SPT[(size_t)t * MM + tid + 256 * i] = e2[i] * inv;
  if (tid == 0) {
    int p = posi[t];
    int widx = wtbl[p * MM + amax];
    int wf = wflat[t];
    int avoid = (widx == wf) ? 1 : 0;
    avoidb[t] = avoid;
    out_word[t] = (float)(avoid ? 0 : widx);
    out_mask[t] = 1.0f;
    out_pri[t] = (p < 4) ? 1.0f : 0.0f;
    rowent[t] = ent;
  }
}

// ---------------- K7: grouped emb GEMM ----------------
__global__ __launch_bounds__(256) void k_embgemm(const float* __restrict__ SPT,
    const float* __restrict__ Ptbl, const float* __restrict__ psrw,
    const int* __restrict__ counts, const int* __restrict__ offs,
    const int* __restrict__ idxlist, const int* __restrict__ avoidb,
    float* __restrict__ out_emb) {
  int p = blockIdx.y;
  int n = counts[p];
  int r0 = blockIdx.x * 64;
  if (r0 >= n) return;
  __shared__ float As[16][68];
  __shared__ float Bs[16][132];
  __shared__ int rows[64];
  int tid = threadIdx.x;
  if (tid < 64) rows[tid] = idxlist[offs[p] + ((r0 + tid) < n ? (r0 + tid) : 0)];
  __syncthreads();
  const float* P = Ptbl + (size_t)p * MM * EE;
  int tx = tid & 31, ty = tid >> 5;
  float acc[8][4] = {};
  for (int k0 = 0; k0 < MM; k0 += 16) {
    int r = tid >> 2, c = (tid & 3) * 4;
    float4 av = *(const float4*)(SPT + (size_t)rows[r] * MM + k0 + c);
    As[c + 0][r] = av.x; As[c + 1][r] = av.y; As[c + 2][r] = av.z; As[c + 3][r] = av.w;
    int r2 = tid >> 4;
    int c2 = (tid & 15) * 8;
    float4 b0 = make_float4(0.f, 0.f, 0.f, 0.f), b1 = make_float4(0.f, 0.f, 0.f, 0.f);
    if (c2 + 3 < EE) b0 = *(const float4*)(P + (size_t)(k0 + r2) * EE + c2);
    if (c2 + 7 < EE) b1 = *(const float4*)(P + (size_t)(k0 + r2) * EE + c2 + 4);
    *(float4*)(&Bs[r2][c2]) = b0;
    *(float4*)(&Bs[r2][c2 + 4]) = b1;
    __syncthreads();
#pragma unroll
    for (int kk = 0; kk < 16; ++kk) {
      float4 b4 = *(const float4*)(&Bs[kk][tx * 4]);
      float4 a0 = *(const float4*)(&As[kk][ty * 8]);
      float4 a1 = *(const float4*)(&As[kk][ty * 8 + 4]);
      float a[8] = {a0.x, a0.y, a0.z, a0.w, a1.x, a1.y, a1.z, a1.w};
#pragma unroll
      for (int ri = 0; ri < 8; ++ri) {
        acc[ri][0] += a[ri] * b4.x; acc[ri][1] += a[ri] * b4.y;
        acc[ri][2] += a[ri] * b4.z; acc[ri][3] += a[ri] * b4.w;
      }
    }
    __syncthreads();
  }
#pragma unroll
  for (int ri = 0; ri < 8; ++ri) {
    int r = ty * 8 + ri;
    if (r0 + r < n) {
      int tok = rows[r];
      int av = avoidb[tok];
#pragma unroll
      for (int j = 0; j < 4; ++j) {
        int col = tx * 4 + j;
        if (col < EE) {
          float v = av ? psrw[col] : acc[ri][j];
          out_emb[(size_t)tok * EE + col] = v;
        }
      }
    }
  }
}

// ---------------- K8: deterministic entropy-loss reduction ----------------
__global__ __launch_bounds__(256) void k_final(const float* __restrict__ rowent,
    const int* __restrict__ posi, const int* __restrict__ counts,
    float* __restrict__ out_loss) {
  __shared__ float red[256];
  int tid = threadIdx.x;
  float s = 0.f;
  for (int t = tid; t < TT; t += 256) {
    int p = posi[t];
    float denom = fmaxf((float)counts[p] * (float)MM, 1.0f);
    s += rowent[t] / denom;
  }
  red[tid] = s; __syncthreads();
  for (int o = 128; o > 0; o >>= 1) { if (tid < o) red[tid] += red[tid + o]; __syncthreads(); }
  if (tid == 0) out_loss[0] = -red[0] * 0.01f;
}

// ---------------- launcher ----------------
extern "C" void kernel_launch(void* const* d_in, const int* in_sizes, int n_in,
                              void* d_out, int out_size, void* d_ws, size_t ws_size,
                              hipStream_t stream) {
  const int*   inp_word = (const int*)d_in[0];
  const int*   inp_pos  = (const int*)d_in[1];
  const float* inp_mask = (const float*)d_in[2];
  const float* gum      = (const float*)d_in[3];
  const float* wemb     = (const float*)d_in[4];
  const float* pemb     = (const float*)d_in[5];
  const float* Wx_f     = (const float*)d_in[6];
  const float* Wh_f     = (const float*)d_in[7];
  const float* b_f      = (const float*)d_in[8];
  const float* Wx_b     = (const float*)d_in[9];
  const float* Wh_b     = (const float*)d_in[10];
  const float* b_b      = (const float*)d_in[11];
  const float* decW     = (const float*)d_in[12];
  const float* decb     = (const float*)d_in[13];
  const int*   wtbl     = (const int*)d_in[14];
  const float* psrw     = (const float*)d_in[15];

  float* out_word = (float*)d_out;
  float* out_emb  = out_word + TT;
  float* out_mask = out_emb + (size_t)TT * EE;
  float* out_pri  = out_mask + TT;
  float* out_loss = out_pri + TT;

  float* ws = (float*)d_ws;
  float* X      = ws;
  float* GXf    = X + (size_t)TT * DIN;
  float* GXb    = GXf + (size_t)TT * G4;
  float* ctxb   = GXb + (size_t)TT * G4;
  unsigned long long* Hpair = (unsigned long long*)(ctxb + (size_t)TT * MM);
  float* rowent = (float*)(Hpair + 65536);
  int* avoidb   = (int*)(rowent + TT);
  int* counts   = avoidb + TT;
  int* offs     = counts + 16;
  int* idxlist  = offs + 32;
  float* Z    = GXf;   // reuse: GX dead after LSTM
  float* SPT  = Z;     // in-place row rewrite in k_softmax
  float* Ptbl = GXb;   // reuse

  k_embed<<<TT, 64, 0, stream>>>(inp_word, inp_pos, wemb, pemb, X);
  k_gemm2<<<dim3(2 * G4 / 128, TT / 128), 256, 0, stream>>>(X, Wx_f, Wx_b, b_f, b_b, GXf, GXb);

  k_initH<<<256, 256, 0, stream>>>(Hpair);
  {
    const int ldsz = 32768;  // max(Wtmp 32KB, Hs+part ~22.7KB)
    hipFuncSetAttribute((const void*)k_lstm7,
                        hipFuncAttributeMaxDynamicSharedMemorySize, ldsz);
    k_lstm7<<<256, 512, ldsz, stream>>>(Wh_f, Wh_b, GXf, GXb, inp_mask, Hpair, ctxb);
  }

  k_zero16<<<1, 64, 0, stream>>>(counts);
  k_count<<<TT / 256, 256, 0, stream>>>(inp_pos, counts);
  k_prefix<<<1, 64, 0, stream>>>(counts, offs);
  k_compact<<<NTAGS, 256, 0, stream>>>(inp_pos, offs, idxlist);
  k_ptbl<<<1024, 256, 0, stream>>>(wtbl, psrw, Ptbl);
  k_decgemm<<<dim3(MM / 64, TT / 64, NTAGS), 256, 0, stream>>>(ctxb, decW, decb, counts, offs, idxlist, Z);
  k_softmax<<<TT, 256, 0, stream>>>(Z, gum, inp_pos, inp_word, wtbl, SPT, rowent, avoidb,
                                    out_word, out_mask, out_pri);
  k_embgemm<<<dim3(TT / 64, NTAGS), 256, 0, stream>>>(SPT, Ptbl, psrw, counts, offs, idxlist,
                                                      avoidb, out_emb);
  k_final<<<1, 256, 0, stream>>>(rowent, inp_pos, counts, out_loss);
}